// Round 6
// baseline (3945.238 us; speedup 1.0000x reference)
//
#include <hip/hip_runtime.h>
#include <math.h>

// ---------------- workspace offsets (bytes) ----------------
#define OFF_CENT   0x0        // int [2][2048]
#define OFF_XSP    0x20000    // float4 [2][2048]
#define OFF_XS6    0x40000    // float [2][2048][6]
#define OFF_KNN    0x60000    // int [2][2048][64] max
#define OFF_F      0x180000   // float [2*2048][512] max
#define OFF_UV     0xA00000   // float [2*2048][1024] max
#define OFF_G      0x1A00000  // float [2*2048][512] max
#define OFF_WCAT   0x2200000  // float [256][1024] max
#define OFF_BCAT   0x2400000  // float [1024]
#define OFF_FUSED  0x2500000  // float [2][4096][1280]  -> ws end 77 MB
#define OFF_T      0x180000   // reuse (post-encoder)
#define OFF_H1     0x1200000  // reuse
#define OFF_T2     0x2200000  // reuse

// ---------------- helpers ----------------
__device__ __forceinline__ unsigned fkey_flip(float f) {
  unsigned u = __float_as_uint(f);
  return u ^ ((u >> 31) ? 0xFFFFFFFFu : 0x80000000u);
}
__device__ __forceinline__ float fkey_unflip(unsigned k) {
  unsigned u = k ^ ((k >> 31) ? 0x80000000u : 0xFFFFFFFFu);
  return __uint_as_float(u);
}

template<int CTRL>
__device__ __forceinline__ float dpp_max_stepf(float v) {
  int t = __builtin_amdgcn_update_dpp(__float_as_int(v), __float_as_int(v),
                                      CTRL, 0xf, 0xf, false);
  return fmaxf(v, __int_as_float(t));
}
__device__ __forceinline__ float wave64_max(float v) {
  v = dpp_max_stepf<0x111>(v);
  v = dpp_max_stepf<0x112>(v);
  v = dpp_max_stepf<0x114>(v);
  v = dpp_max_stepf<0x118>(v);
  v = dpp_max_stepf<0x142>(v);
  v = dpp_max_stepf<0x143>(v);
  return __int_as_float(__builtin_amdgcn_readlane(__float_as_int(v), 63));
}
template<int CTRL>
__device__ __forceinline__ float dpp_min_stepf(float v) {
  int t = __builtin_amdgcn_update_dpp(__float_as_int(v), __float_as_int(v),
                                      CTRL, 0xf, 0xf, false);
  return fminf(v, __int_as_float(t));
}
__device__ __forceinline__ float wave64_min(float v) {
  v = dpp_min_stepf<0x111>(v);
  v = dpp_min_stepf<0x112>(v);
  v = dpp_min_stepf<0x114>(v);
  v = dpp_min_stepf<0x118>(v);
  v = dpp_min_stepf<0x142>(v);
  v = dpp_min_stepf<0x143>(v);
  return __int_as_float(__builtin_amdgcn_readlane(__float_as_int(v), 63));
}
template<int CTRL>
__device__ __forceinline__ unsigned dpp_min_stepu(unsigned v) {
  unsigned t = (unsigned)__builtin_amdgcn_update_dpp((int)v, (int)v,
                                                     CTRL, 0xf, 0xf, false);
  return v < t ? v : t;
}
__device__ __forceinline__ unsigned wave64_min_u32(unsigned v) {
  v = dpp_min_stepu<0x111>(v);
  v = dpp_min_stepu<0x112>(v);
  v = dpp_min_stepu<0x114>(v);
  v = dpp_min_stepu<0x118>(v);
  v = dpp_min_stepu<0x142>(v);
  v = dpp_min_stepu<0x143>(v);
  return (unsigned)__builtin_amdgcn_readlane((int)v, 63);
}
__device__ __forceinline__ unsigned long long u64max(unsigned long long a,
                                                    unsigned long long b) {
  return a > b ? a : b;
}
__device__ __forceinline__ unsigned spread3(unsigned v) {
  return (v & 1u) | ((v & 2u) << 2) | ((v & 4u) << 4);
}

// ---------------- FPS with chunk pruning: one block per batch ----------------
// Setup: spatial counting sort (8^3 Morton cells) -> 64 chunks of 64 consecutive
// sorted points (one wave register each) + chunk bboxes.
// Per iteration: lanes 0..7 bound-check their chunk (conservative margin);
// only failing chunks run the exact _rn distance update + DPP argmax refresh.
// Cached per-chunk candidate (val, origidx, sortedpos) otherwise reused.
// Selection semantics identical to reference: max value, ties -> lowest orig idx.
__global__ __launch_bounds__(512) void fps_kernel(const float* __restrict__ x,
                                                  int* __restrict__ cent)
{
  int b = blockIdx.x, tid = threadIdx.x;
  int wid = tid >> 6, lane = tid & 63;
  __shared__ float4 ss4[4096];                 // sorted (x,y,z,asfloat(origidx))
  __shared__ float bb[64 * 6];                 // chunk bboxes
  __shared__ unsigned hist[512];
  __shared__ unsigned sc[512];
  __shared__ unsigned bbm[6];                  // flipped-u32 global bbox
  __shared__ __align__(16) unsigned long long slots[2][8];

  // ---- load original points ----
  float px[8], py[8], pz[8], dist[8];
  unsigned spk[8];
#pragma unroll
  for (int i = 0; i < 8; ++i) {
    int p = tid + 512 * i;
    const float* r = x + ((long)b * 4096 + p) * 6;
    px[i] = r[0]; py[i] = r[1]; pz[i] = r[2];
  }
  if (tid < 6) bbm[tid] = (tid < 3) ? 0xFFFFFFFFu : 0u;
  if (tid < 512) hist[tid] = 0u;
  if (tid == 0) cent[b * 2048] = 0;
  __syncthreads();

  // ---- global bbox (flipped-u32 atomics; grouping only, any rounding ok) ----
  {
    float lx = px[0], hx = px[0], ly = py[0], hy = py[0], lz = pz[0], hz = pz[0];
#pragma unroll
    for (int i = 1; i < 8; ++i) {
      lx = fminf(lx, px[i]); hx = fmaxf(hx, px[i]);
      ly = fminf(ly, py[i]); hy = fmaxf(hy, py[i]);
      lz = fminf(lz, pz[i]); hz = fmaxf(hz, pz[i]);
    }
    lx = wave64_min(lx); hx = wave64_max(hx);
    ly = wave64_min(ly); hy = wave64_max(hy);
    lz = wave64_min(lz); hz = wave64_max(hz);
    if (lane == 0) {
      atomicMin(&bbm[0], fkey_flip(lx)); atomicMax(&bbm[3], fkey_flip(hx));
      atomicMin(&bbm[1], fkey_flip(ly)); atomicMax(&bbm[4], fkey_flip(hy));
      atomicMin(&bbm[2], fkey_flip(lz)); atomicMax(&bbm[5], fkey_flip(hz));
    }
  }
  __syncthreads();
  float lox = fkey_unflip(bbm[0]), loy = fkey_unflip(bbm[1]), loz = fkey_unflip(bbm[2]);
  float hix = fkey_unflip(bbm[3]), hiy = fkey_unflip(bbm[4]), hiz = fkey_unflip(bbm[5]);
  float sxf = (hix > lox) ? 8.0f / (hix - lox) : 0.0f;
  float syf = (hiy > loy) ? 8.0f / (hiy - loy) : 0.0f;
  float szf = (hiz > loz) ? 8.0f / (hiz - loz) : 0.0f;

  // ---- histogram ----
#pragma unroll
  for (int i = 0; i < 8; ++i) {
    int ix = min(7, max(0, (int)((px[i] - lox) * sxf)));
    int iy = min(7, max(0, (int)((py[i] - loy) * syf)));
    int iz = min(7, max(0, (int)((pz[i] - loz) * szf)));
    unsigned cell = spread3((unsigned)ix) | (spread3((unsigned)iy) << 1)
                  | (spread3((unsigned)iz) << 2);
    atomicAdd(&hist[cell], 1u);
  }
  __syncthreads();

  // ---- exclusive scan of hist (Hillis-Steele, 512 threads) ----
  unsigned myc = hist[tid];
  unsigned run = myc;
  for (int s = 1; s < 512; s <<= 1) {
    sc[tid] = run;
    __syncthreads();
    if (tid >= s) run += sc[tid - s];
    __syncthreads();
  }
  hist[tid] = run - myc;     // exclusive start, becomes running cursor
  __syncthreads();

  // ---- scatter ----
#pragma unroll
  for (int i = 0; i < 8; ++i) {
    int ix = min(7, max(0, (int)((px[i] - lox) * sxf)));
    int iy = min(7, max(0, (int)((py[i] - loy) * syf)));
    int iz = min(7, max(0, (int)((pz[i] - loz) * szf)));
    unsigned cell = spread3((unsigned)ix) | (spread3((unsigned)iy) << 1)
                  | (spread3((unsigned)iz) << 2);
    unsigned pos = atomicAdd(&hist[cell], 1u);
    ss4[pos] = make_float4(px[i], py[i], pz[i],
                           __uint_as_float((unsigned)(tid + 512 * i)));
  }
  __syncthreads();

  // ---- reload in sorted order; chunk (wid,i) = positions wid*512+i*64+lane ----
#pragma unroll
  for (int i = 0; i < 8; ++i) {
    int pos = wid * 512 + i * 64 + lane;
    float4 c = ss4[pos];
    px[i] = c.x; py[i] = c.y; pz[i] = c.z;
    unsigned oidx = __float_as_uint(c.w);
    spk[i] = (oidx << 12) | (unsigned)pos;   // orig-idx-major packed key
    dist[i] = 1e10f;
  }

  // ---- chunk bboxes ----
#pragma unroll
  for (int i = 0; i < 8; ++i) {
    float lx = wave64_min(px[i]), hx = wave64_max(px[i]);
    float ly = wave64_min(py[i]), hy = wave64_max(py[i]);
    float lz = wave64_min(pz[i]), hz = wave64_max(pz[i]);
    if (lane == 0) {
      float* bp = &bb[(wid * 8 + i) * 6];
      bp[0] = lx; bp[1] = hx; bp[2] = ly; bp[3] = hy; bp[4] = lz; bp[5] = hz;
    }
  }
  // candidates: lane j holds chunk j of this wave
  float candval = 1e10f;
  unsigned candpk = 0;
#pragma unroll
  for (int i = 0; i < 8; ++i) {
    unsigned im = wave64_min_u32(spk[i]);
    if (lane == i) candpk = im;
  }
  float blox = 0, bhxx = 0, bloy = 0, bhxy = 0, bloz = 0, bhxz = 0;
  __syncthreads();
  if (lane < 8) {
    const float* bp = &bb[(wid * 8 + lane) * 6];
    blox = bp[0]; bhxx = bp[1]; bloy = bp[2]; bhxy = bp[3]; bloz = bp[4]; bhxz = bp[5];
  }

  // ---- initial centroid = original point 0 ----
  const float* r0 = x + (long)b * 4096 * 6;
  float cx = r0[0], cy = r0[1], cz = r0[2];

  // ---- main loop ----
  for (int j = 1; j < 2048; ++j) {
    // bound check (lanes 0..7); conservative margin keeps skips exact-safe
    float dxm = fmaxf(fmaxf(blox - cx, cx - bhxx), 0.0f);
    float dym = fmaxf(fmaxf(bloy - cy, cy - bhxy), 0.0f);
    float dzm = fmaxf(fmaxf(bloz - cz, cz - bhxz), 0.0f);
    float md2 = dxm * dxm + dym * dym + dzm * dzm;
    bool upd = (lane < 8) && (md2 * 0.99999f < candval);
    unsigned long long umask = __ballot(upd) & 0xFFull;
    if (umask) {
#pragma unroll
      for (int i = 0; i < 8; ++i) {
        if (umask & (1ull << i)) {
          // exact replica of sum((xyz-c)**2,-1): ((dx*dx+dy*dy)+dz*dz), no FMA
          float dx = __fsub_rn(px[i], cx);
          float dy = __fsub_rn(py[i], cy);
          float dz = __fsub_rn(pz[i], cz);
          float d  = __fadd_rn(__fadd_rn(__fmul_rn(dx, dx), __fmul_rn(dy, dy)),
                               __fmul_rn(dz, dz));
          float nd = fminf(dist[i], d);
          dist[i] = nd;
          float vm = wave64_max(nd);
          unsigned mi = (nd == vm) ? spk[i] : 0xFFFFFFFFu;
          unsigned im = wave64_min_u32(mi);
          if (lane == i) { candval = vm; candpk = im; }
        }
      }
    }
    // merge 8 chunk candidates: key = (val<<24) | (~oidx)<<12 | pos  (56 bits)
    unsigned long long best = 0ULL;
#pragma unroll
    for (int l = 0; l < 8; ++l) {
      unsigned vb = (unsigned)__builtin_amdgcn_readlane(__float_as_int(candval), l);
      unsigned pk = (unsigned)__builtin_amdgcn_readlane((int)candpk, l);
      unsigned long long key = ((unsigned long long)vb << 24)
                             | (unsigned long long)(((~(pk >> 12)) & 0xFFFu) << 12)
                             | (unsigned long long)(pk & 0xFFFu);
      best = u64max(best, key);
    }
    if (lane == 0) slots[j & 1][wid] = best;
    __syncthreads();                       // the only barrier per iteration
    const unsigned long long* sl = slots[j & 1];
    ulonglong2 sA = *(const ulonglong2*)&sl[0];
    ulonglong2 sB = *(const ulonglong2*)&sl[2];
    ulonglong2 sC = *(const ulonglong2*)&sl[4];
    ulonglong2 sD = *(const ulonglong2*)&sl[6];
    unsigned long long kk = u64max(u64max(u64max(sA.x, sA.y), u64max(sB.x, sB.y)),
                                   u64max(u64max(sC.x, sC.y), u64max(sD.x, sD.y)));
    unsigned pos  = (unsigned)(kk & 0xFFFu);
    unsigned oidx = (~((unsigned)(kk >> 12))) & 0xFFFu;
    float4 c = ss4[pos];
    cx = c.x; cy = c.y; cz = c.z;
    if (tid == 0) cent[b * 2048 + j] = (int)oidx;
  }
}

// ---------------- gather subsampled points ----------------
__global__ void gather_xs_kernel(const float* __restrict__ x, const int* __restrict__ cent,
                                 float* __restrict__ xs6, float4* __restrict__ xsp)
{
  int t = blockIdx.x * 256 + threadIdx.x;
  if (t >= 2 * 2048) return;
  int b = t >> 11;
  int p = cent[t];
  const float* src = x + ((long)b * 4096 + p) * 6;
  float* dst = xs6 + (long)t * 6;
#pragma unroll
  for (int c = 0; c < 6; ++c) dst[c] = src[c];
  xsp[t] = make_float4(src[0], src[1], src[2], 0.0f);
}

// ---------------- kNN: one wave per query ----------------
template<int S, int K>
__global__ __launch_bounds__(256) void knn_kernel(const float4* __restrict__ xsp,
                                                  int* __restrict__ out)
{
  constexpr int NI = S / 64;
  __shared__ float4 P[S];
  int b = (blockIdx.x * 4) / S;
  int wid = threadIdx.x >> 6, lane = threadIdx.x & 63;
  int s = (blockIdx.x * 4 + wid) & (S - 1);
  for (int i = threadIdx.x; i < S; i += 256) P[i] = xsp[b * 2048 + i];
  __syncthreads();
  float4 Q = P[s];
  float saq = __fadd_rn(__fadd_rn(__fmul_rn(Q.x,Q.x), __fmul_rn(Q.y,Q.y)), __fmul_rn(Q.z,Q.z));
  float dd[NI];
#pragma unroll
  for (int i = 0; i < NI; ++i) {
    float4 c = P[i * 64 + lane];
    float sac = __fadd_rn(__fadd_rn(__fmul_rn(c.x,c.x), __fmul_rn(c.y,c.y)), __fmul_rn(c.z,c.z));
    float dot = __fadd_rn(__fadd_rn(__fmul_rn(Q.x,c.x), __fmul_rn(Q.y,c.y)), __fmul_rn(Q.z,c.z));
    dd[i] = __fsub_rn(__fadd_rn(saq, sac), __fmul_rn(2.0f, dot));
  }
  long obase = ((long)b * S + s) * K;
  for (int t = 0; t < K; ++t) {
    float bv = INFINITY; int bi = 0;
#pragma unroll
    for (int i = 0; i < NI; ++i) if (dd[i] < bv) { bv = dd[i]; bi = i; }
    unsigned long long key = ((unsigned long long)fkey_flip(bv) << 32)
                           | (unsigned)(bi * 64 + lane);
#pragma unroll
    for (int m = 32; m; m >>= 1) {
      unsigned long long o = __shfl_xor(key, m, 64);
      if (o < key) key = o;
    }
    unsigned cand = (unsigned)key;
    if ((int)(cand & 63) == lane) {
      int slot = cand >> 6;
#pragma unroll
      for (int i = 0; i < NI; ++i) if (i == slot) dd[i] = INFINITY;
    }
    if (lane == 0) out[obase + t] = (int)cand;
  }
}

// ---------------- Wcat prep ----------------
__global__ void wcat_prep(const float* __restrict__ W, const float* __restrict__ bias,
                          int C, int Cp, float* __restrict__ Wcat, float* __restrict__ bcat)
{
  int n2 = 2 * Cp;
  int total = C * n2;
  for (int t = blockIdx.x * 256 + threadIdx.x; t < total + n2; t += gridDim.x * 256) {
    if (t < total) {
      int c = t / n2, n = t % n2;
      Wcat[t] = (n < Cp) ? (W[c * Cp + n] - W[(C + c) * Cp + n]) : W[(C + c) * Cp + (n - Cp)];
    } else {
      int n = t - total;
      bcat[n] = (n < Cp) ? bias[n] : 0.0f;
    }
  }
}

// ---------------- generic fp32 GEMM (64x64 tile) ----------------
__global__ __launch_bounds__(256) void gemm_bias(
    const float* __restrict__ A, long strideA, int lda,
    const float* __restrict__ W, int N, int K,
    const float* __restrict__ bias,
    float* __restrict__ C, long strideC, int ldc)
{
  A += (long)blockIdx.z * strideA;
  C += (long)blockIdx.z * strideC;
  int rowBase = blockIdx.x * 64, colBase = blockIdx.y * 64;
  __shared__ float As[16][68];
  __shared__ float Ws[16][68];
  int tid = threadIdx.x;
  int tx = tid & 15, ty = tid >> 4;
  float acc[4][4] = {};
  for (int k0 = 0; k0 < K; k0 += 16) {
    {
      int r = tid >> 2, c0 = (tid & 3) * 4;
      const float* Ar = A + (long)(rowBase + r) * lda + k0 + c0;
#pragma unroll
      for (int u = 0; u < 4; ++u) {
        float val = 0.0f;
        if (k0 + c0 + u < K) val = Ar[u];
        As[c0 + u][r] = val;
      }
    }
    {
      int c = tid & 63, kr = tid >> 6;
#pragma unroll
      for (int u = 0; u < 4; ++u) {
        int kk = kr + u * 4;
        float val = 0.0f;
        if (k0 + kk < K) val = W[(long)(k0 + kk) * N + colBase + c];
        Ws[kk][c] = val;
      }
    }
    __syncthreads();
#pragma unroll
    for (int kk = 0; kk < 16; ++kk) {
      float4 av = *(const float4*)&As[kk][ty * 4];
      float4 wv = *(const float4*)&Ws[kk][tx * 4];
      float a_[4] = {av.x, av.y, av.z, av.w};
      float w_[4] = {wv.x, wv.y, wv.z, wv.w};
#pragma unroll
      for (int i = 0; i < 4; ++i)
#pragma unroll
        for (int j = 0; j < 4; ++j)
          acc[i][j] = fmaf(a_[i], w_[j], acc[i][j]);
    }
    __syncthreads();
  }
#pragma unroll
  for (int i = 0; i < 4; ++i) {
    int r = rowBase + ty * 4 + i;
    int c0 = colBase + tx * 4;
    float4 o;
    o.x = acc[i][0] + bias[c0 + 0];
    o.y = acc[i][1] + bias[c0 + 1];
    o.z = acc[i][2] + bias[c0 + 2];
    o.w = acc[i][3] + bias[c0 + 3];
    *(float4*)&C[(long)r * ldc + c0] = o;
  }
}

// ---------------- big fp32 GEMM: 128x128 tile, 8x8 acc/thread ----------------
__global__ __launch_bounds__(256) void gemm_bias_big(
    const float* __restrict__ A, int lda,
    const float* __restrict__ W, int N, int K,
    const float* __restrict__ bias,
    float* __restrict__ C, int ldc)
{
  int rowBase = blockIdx.x * 128, colBase = blockIdx.y * 128;
  __shared__ float As[16][132];
  __shared__ float Ws[16][132];
  int tid = threadIdx.x;
  int tx = tid & 15, ty = tid >> 4;
  float acc[8][8] = {};
  for (int k0 = 0; k0 < K; k0 += 16) {
    {
      int r = tid >> 1, c0 = (tid & 1) * 8;
      const float* Ar = A + (long)(rowBase + r) * lda + k0 + c0;
      float4 v0 = *(const float4*)(Ar);
      float4 v1 = *(const float4*)(Ar + 4);
      As[c0 + 0][r] = v0.x; As[c0 + 1][r] = v0.y; As[c0 + 2][r] = v0.z; As[c0 + 3][r] = v0.w;
      As[c0 + 4][r] = v1.x; As[c0 + 5][r] = v1.y; As[c0 + 6][r] = v1.z; As[c0 + 7][r] = v1.w;
    }
    {
      int kr = tid >> 4, c0 = (tid & 15) * 8;
      const float* Wr = W + (long)(k0 + kr) * N + colBase + c0;
      float4 w0 = *(const float4*)(Wr);
      float4 w1 = *(const float4*)(Wr + 4);
      *(float4*)&Ws[kr][c0]     = w0;
      *(float4*)&Ws[kr][c0 + 4] = w1;
    }
    __syncthreads();
#pragma unroll
    for (int kk = 0; kk < 16; ++kk) {
      float a_[8], w_[8];
      *(float4*)&a_[0] = *(const float4*)&As[kk][ty * 8];
      *(float4*)&a_[4] = *(const float4*)&As[kk][ty * 8 + 4];
      *(float4*)&w_[0] = *(const float4*)&Ws[kk][tx * 8];
      *(float4*)&w_[4] = *(const float4*)&Ws[kk][tx * 8 + 4];
#pragma unroll
      for (int i = 0; i < 8; ++i)
#pragma unroll
        for (int jj = 0; jj < 8; ++jj)
          acc[i][jj] = fmaf(a_[i], w_[jj], acc[i][jj]);
    }
    __syncthreads();
  }
#pragma unroll
  for (int i = 0; i < 8; ++i) {
    int r = rowBase + ty * 8 + i;
    int c0 = colBase + tx * 8;
    float4 o0, o1;
    o0.x = acc[i][0] + bias[c0 + 0];
    o0.y = acc[i][1] + bias[c0 + 1];
    o0.z = acc[i][2] + bias[c0 + 2];
    o0.w = acc[i][3] + bias[c0 + 3];
    o1.x = acc[i][4] + bias[c0 + 4];
    o1.y = acc[i][5] + bias[c0 + 5];
    o1.z = acc[i][6] + bias[c0 + 6];
    o1.w = acc[i][7] + bias[c0 + 7];
    *(float4*)&C[(long)r * ldc + c0]     = o0;
    *(float4*)&C[(long)r * ldc + c0 + 4] = o1;
  }
}

// ---------------- edge aggregation (float4): F[s] = relu(u[s] + max_j v[nbr_j]) ----------------
__global__ void edge_agg(const float* __restrict__ UV, const int* __restrict__ idx,
                         int S, int k, int Cp, float* __restrict__ F)
{
  int bs = blockIdx.x;
  int b = bs / S;
  __shared__ int nb[64];
  if ((int)threadIdx.x < k) nb[threadIdx.x] = idx[(long)bs * k + threadIdx.x];
  __syncthreads();
  int ld = 2 * Cp;
  int nf4 = Cp >> 2;
  for (int c4 = threadIdx.x; c4 < nf4; c4 += blockDim.x) {
    float4 m = make_float4(-INFINITY, -INFINITY, -INFINITY, -INFINITY);
    for (int j = 0; j < k; ++j) {
      const float4* vp = (const float4*)(UV + (long)(b * S + nb[j]) * ld + Cp);
      float4 v = vp[c4];
      m.x = fmaxf(m.x, v.x); m.y = fmaxf(m.y, v.y);
      m.z = fmaxf(m.z, v.z); m.w = fmaxf(m.w, v.w);
    }
    float4 u = ((const float4*)(UV + (long)bs * ld))[c4];
    float4 o;
    o.x = u.x + m.x; o.y = u.y + m.y; o.z = u.z + m.z; o.w = u.w + m.w;
    o.x = o.x > 0.0f ? o.x : 0.0f;
    o.y = o.y > 0.0f ? o.y : 0.0f;
    o.z = o.z > 0.0f ? o.z : 0.0f;
    o.w = o.w > 0.0f ? o.w : 0.0f;
    ((float4*)(F + (long)bs * Cp))[c4] = o;
  }
}

// ---------------- upsample (float4 gather): 3-NN inverse-distance interp ----------------
template<int S, int CP>
__global__ __launch_bounds__(256) void upsample_kernel(
    const float* __restrict__ x, const float4* __restrict__ xsp,
    const float* __restrict__ G, float* __restrict__ fused, int colOff)
{
  constexpr int NI = S / 64;
  __shared__ float4 P[S];
  int b = (blockIdx.x * 4) >> 12;
  int wid = threadIdx.x >> 6, lane = threadIdx.x & 63;
  int n = (blockIdx.x * 4 + wid) & 4095;
  for (int i = threadIdx.x; i < S; i += 256) P[i] = xsp[b * 2048 + i];
  __syncthreads();
  const float* q = x + ((long)b * 4096 + n) * 6;
  float qx = q[0], qy = q[1], qz = q[2];
  float saq = __fadd_rn(__fadd_rn(__fmul_rn(qx,qx), __fmul_rn(qy,qy)), __fmul_rn(qz,qz));
  float dd[NI];
#pragma unroll
  for (int i = 0; i < NI; ++i) {
    float4 c = P[i * 64 + lane];
    float sac = __fadd_rn(__fadd_rn(__fmul_rn(c.x,c.x), __fmul_rn(c.y,c.y)), __fmul_rn(c.z,c.z));
    float dot = __fadd_rn(__fadd_rn(__fmul_rn(qx,c.x), __fmul_rn(qy,c.y)), __fmul_rn(qz,c.z));
    dd[i] = __fsub_rn(__fadd_rn(saq, sac), __fmul_rn(2.0f, dot));
  }
  int id[3]; float w[3];
  for (int t = 0; t < 3; ++t) {
    float bv = INFINITY; int bi = 0;
#pragma unroll
    for (int i = 0; i < NI; ++i) if (dd[i] < bv) { bv = dd[i]; bi = i; }
    unsigned long long key = ((unsigned long long)fkey_flip(bv) << 32)
                           | (unsigned)(bi * 64 + lane);
#pragma unroll
    for (int m = 32; m; m >>= 1) {
      unsigned long long o = __shfl_xor(key, m, 64);
      if (o < key) key = o;
    }
    unsigned cand = (unsigned)key;
    float d2 = fkey_unflip((unsigned)(key >> 32));
    float d = __fsqrt_rn(fmaxf(d2, 0.0f));
    id[t] = (int)cand;
    w[t] = 1.0f / __fadd_rn(d, 1e-8f);
    if ((int)(cand & 63) == lane) {
      int slot = cand >> 6;
#pragma unroll
      for (int i = 0; i < NI; ++i) if (i == slot) dd[i] = INFINITY;
    }
  }
  float wsum = __fadd_rn(__fadd_rn(w[0], w[1]), w[2]);
  float w0 = w[0] / wsum, w1 = w[1] / wsum, w2 = w[2] / wsum;
  const float4* g0 = (const float4*)(G + (long)(b * S + id[0]) * CP);
  const float4* g1 = (const float4*)(G + (long)(b * S + id[1]) * CP);
  const float4* g2 = (const float4*)(G + (long)(b * S + id[2]) * CP);
  float4* orow = (float4*)(fused + ((long)b * 4096 + n) * 1280 + colOff);
#pragma unroll
  for (int t = 0; t < CP / 256; ++t) {
    int c4 = lane + 64 * t;
    float4 a = g0[c4], bb4 = g1[c4], cc = g2[c4];
    float4 v;
    v.x = __fadd_rn(__fadd_rn(__fmul_rn(w0, a.x), __fmul_rn(w1, bb4.x)), __fmul_rn(w2, cc.x));
    v.y = __fadd_rn(__fadd_rn(__fmul_rn(w0, a.y), __fmul_rn(w1, bb4.y)), __fmul_rn(w2, cc.y));
    v.z = __fadd_rn(__fadd_rn(__fmul_rn(w0, a.z), __fmul_rn(w1, bb4.z)), __fmul_rn(w2, cc.z));
    v.w = __fadd_rn(__fadd_rn(__fmul_rn(w0, a.w), __fmul_rn(w1, bb4.w)), __fmul_rn(w2, cc.w));
    orow[c4] = v;
  }
}

// ---------------- GroupNorm(32,512) + relu (+ optional pos-enc) ----------------
__global__ __launch_bounds__(256) void gn_kernel(const float* __restrict__ T,
    const float* __restrict__ gw, const float* __restrict__ gb,
    float* __restrict__ out, int addPos)
{
  int t = blockIdx.x * 256 + threadIdx.x;
  int row = t >> 5, g = t & 31;
  const float* p = T + (long)row * 512 + g * 16;
  float v[16];
#pragma unroll
  for (int i = 0; i < 4; ++i) {
    float4 f = *(const float4*)(p + i * 4);
    v[i*4+0] = f.x; v[i*4+1] = f.y; v[i*4+2] = f.z; v[i*4+3] = f.w;
  }
  float s = 0.0f;
#pragma unroll
  for (int i = 0; i < 16; ++i) s += v[i];
  float mu = s * 0.0625f;
  float var = 0.0f;
#pragma unroll
  for (int i = 0; i < 16; ++i) { float d = v[i] - mu; var += d * d; }
  var *= 0.0625f;
  float inv = 1.0f / sqrtf(var + 1e-5f);
  int cbase = g * 16;
  int n = row & 4095;
  float o[16];
#pragma unroll
  for (int i = 0; i < 16; ++i) {
    int c = cbase + i;
    float y = (v[i] - mu) * inv * gw[c] + gb[c];
    y = y > 0.0f ? y : 0.0f;
    if (addPos) {
      int half = c >> 1;
      float div = expf((float)(2 * half) * -0.017988946039016358f); // -ln(10000)/512
      float ang = (float)n * div;
      y += (c & 1) ? cosf(ang) : sinf(ang);
    }
    o[i] = y;
  }
  float* d = out + (long)row * 512 + cbase;
#pragma unroll
  for (int i = 0; i < 4; ++i) {
    float4 f; f.x = o[i*4+0]; f.y = o[i*4+1]; f.z = o[i*4+2]; f.w = o[i*4+3];
    *(float4*)(d + i * 4) = f;
  }
}

// ---------------- host-side launch helpers ----------------
static inline void launch_gemm(const float* A, long strideA, int lda,
                               const float* W, const float* bias,
                               float* C, long strideC, int ldc,
                               int Mb, int N, int K, int nb, hipStream_t s)
{
  dim3 grid(Mb / 64, N / 64, nb);
  gemm_bias<<<grid, 256, 0, s>>>(A, strideA, lda, W, N, K, bias, C, strideC, ldc);
}
static inline void launch_gemm_big(const float* A, int lda,
                                   const float* W, const float* bias,
                                   float* C, int ldc,
                                   int M, int N, int K, hipStream_t s)
{
  dim3 grid(M / 128, N / 128, 1);
  gemm_bias_big<<<grid, 256, 0, s>>>(A, lda, W, N, K, bias, C, ldc);
}
static inline void launch_edge(const float* UV, const int* knn, int S, int k, int Cp,
                               float* F, hipStream_t s)
{
  int threads = Cp / 4 < 64 ? 64 : Cp / 4;
  edge_agg<<<dim3(2 * S), threads, 0, s>>>(UV, knn, S, k, Cp, F);
}

extern "C" void kernel_launch(void* const* d_in, const int* in_sizes, int n_in,
                              void* d_out, int out_size, void* d_ws, size_t ws_size,
                              hipStream_t stream)
{
  const float* x     = (const float*)d_in[0];
  const float* e1_W0 = (const float*)d_in[1];  const float* e1_b0 = (const float*)d_in[2];
  const float* e1_W1 = (const float*)d_in[3];  const float* e1_b1 = (const float*)d_in[4];
  const float* e1_Wo = (const float*)d_in[5];  const float* e1_bo = (const float*)d_in[6];
  const float* e2_W0 = (const float*)d_in[7];  const float* e2_b0 = (const float*)d_in[8];
  const float* e2_W1 = (const float*)d_in[9];  const float* e2_b1 = (const float*)d_in[10];
  const float* e2_Wo = (const float*)d_in[11]; const float* e2_bo = (const float*)d_in[12];
  const float* e3_W0 = (const float*)d_in[13]; const float* e3_b0 = (const float*)d_in[14];
  const float* e3_W1 = (const float*)d_in[15]; const float* e3_b1 = (const float*)d_in[16];
  const float* e3_W2 = (const float*)d_in[17]; const float* e3_b2 = (const float*)d_in[18];
  const float* e3_Wo = (const float*)d_in[19]; const float* e3_bo = (const float*)d_in[20];
  const float* f_W1  = (const float*)d_in[21]; const float* f_b1  = (const float*)d_in[22];
  const float* g1_w  = (const float*)d_in[23]; const float* g1_b  = (const float*)d_in[24];
  const float* f_W2  = (const float*)d_in[25]; const float* f_b2  = (const float*)d_in[26];
  const float* g2_w  = (const float*)d_in[27]; const float* g2_b  = (const float*)d_in[28];

  char* ws = (char*)d_ws;
  int*    cent  = (int*)(ws + OFF_CENT);
  float4* xsp   = (float4*)(ws + OFF_XSP);
  float*  xs6   = (float*)(ws + OFF_XS6);
  int*    knn   = (int*)(ws + OFF_KNN);
  float*  F     = (float*)(ws + OFF_F);
  float*  UV    = (float*)(ws + OFF_UV);
  float*  G     = (float*)(ws + OFF_G);
  float*  WCAT  = (float*)(ws + OFF_WCAT);
  float*  BCAT  = (float*)(ws + OFF_BCAT);
  float*  FUSED = (float*)(ws + OFF_FUSED);
  float*  T     = (float*)(ws + OFF_T);
  float*  H1    = (float*)(ws + OFF_H1);
  float*  T2    = (float*)(ws + OFF_T2);

  fps_kernel<<<2, 512, 0, stream>>>(x, cent);
  gather_xs_kernel<<<16, 256, 0, stream>>>(x, cent, xs6, xsp);

  // ---- encoder 1: S=512, k=16, 6->128->256, proj 256 ----
  knn_kernel<512,16><<<256, 256, 0, stream>>>(xsp, knn);
  wcat_prep<<<256, 256, 0, stream>>>(e1_W0, e1_b0, 6, 128, WCAT, BCAT);
  launch_gemm(xs6, (long)2048*6, 6, WCAT, BCAT, UV, (long)512*256, 256, 512, 256, 6, 2, stream);
  launch_edge(UV, knn, 512, 16, 128, F, stream);
  wcat_prep<<<256, 256, 0, stream>>>(e1_W1, e1_b1, 128, 256, WCAT, BCAT);
  launch_gemm(F, 0, 128, WCAT, BCAT, UV, 0, 512, 1024, 512, 128, 1, stream);
  launch_edge(UV, knn, 512, 16, 256, F, stream);
  launch_gemm(F, 0, 256, e1_Wo, e1_bo, G, 0, 256, 1024, 256, 256, 1, stream);
  upsample_kernel<512,256><<<2048, 256, 0, stream>>>(x, xsp, G, FUSED, 0);

  // ---- encoder 2: S=1024, k=32, 6->256->512, proj 512 ----
  knn_kernel<1024,32><<<512, 256, 0, stream>>>(xsp, knn);
  wcat_prep<<<256, 256, 0, stream>>>(e2_W0, e2_b0, 6, 256, WCAT, BCAT);
  launch_gemm(xs6, (long)2048*6, 6, WCAT, BCAT, UV, (long)1024*512, 512, 1024, 512, 6, 2, stream);
  launch_edge(UV, knn, 1024, 32, 256, F, stream);
  wcat_prep<<<256, 256, 0, stream>>>(e2_W1, e2_b1, 256, 512, WCAT, BCAT);
  launch_gemm_big(F, 256, WCAT, BCAT, UV, 1024, 2048, 1024, 256, stream);
  launch_edge(UV, knn, 1024, 32, 512, F, stream);
  launch_gemm(F, 0, 512, e2_Wo, e2_bo, G, 0, 512, 2048, 512, 512, 1, stream);
  upsample_kernel<1024,512><<<2048, 256, 0, stream>>>(x, xsp, G, FUSED, 256);

  // ---- encoder 3: S=2048, k=64, 6->128->256->512, proj 512 ----
  knn_kernel<2048,64><<<1024, 256, 0, stream>>>(xsp, knn);
  wcat_prep<<<256, 256, 0, stream>>>(e3_W0, e3_b0, 6, 128, WCAT, BCAT);
  launch_gemm(xs6, (long)2048*6, 6, WCAT, BCAT, UV, (long)2048*256, 256, 2048, 256, 6, 2, stream);
  launch_edge(UV, knn, 2048, 64, 128, F, stream);
  wcat_prep<<<256, 256, 0, stream>>>(e3_W1, e3_b1, 128, 256, WCAT, BCAT);
  launch_gemm_big(F, 128, WCAT, BCAT, UV, 512, 4096, 512, 128, stream);
  launch_edge(UV, knn, 2048, 64, 256, F, stream);
  wcat_prep<<<256, 256, 0, stream>>>(e3_W2, e3_b2, 256, 512, WCAT, BCAT);
  launch_gemm_big(F, 256, WCAT, BCAT, UV, 1024, 4096, 1024, 256, stream);
  launch_edge(UV, knn, 2048, 64, 512, F, stream);
  launch_gemm_big(F, 512, e3_Wo, e3_bo, G, 512, 4096, 512, 512, stream);
  upsample_kernel<2048,512><<<2048, 256, 0, stream>>>(x, xsp, G, FUSED, 768);

  // ---- fusion MLP + GroupNorm + pos-enc ----
  launch_gemm_big(FUSED, 1280, f_W1, f_b1, T, 512, 8192, 512, 1280, stream);
  gn_kernel<<<1024, 256, 0, stream>>>(T, g1_w, g1_b, H1, 0);
  launch_gemm_big(H1, 512, f_W2, f_b2, T2, 512, 8192, 512, 512, stream);
  gn_kernel<<<1024, 256, 0, stream>>>(T2, g2_w, g2_b, (float*)d_out, 1);
}

// Round 7
// 2422.337 us; speedup vs baseline: 1.6287x; 1.6287x over previous
//
#include <hip/hip_runtime.h>
#include <math.h>

// ---------------- workspace offsets (bytes) ----------------
#define OFF_CENT   0x0        // int [2][2048]
#define OFF_XSP    0x20000    // float4 [2][2048]
#define OFF_XS6    0x40000    // float [2][2048][6]
#define OFF_KNN    0x60000    // int [2][2048][64] max
#define OFF_F      0x180000   // float [2*2048][512] max
#define OFF_UV     0xA00000   // float [2*2048][1024] max
#define OFF_G      0x1A00000  // float [2*2048][512] max
#define OFF_WCAT   0x2200000  // float [256][1024] max
#define OFF_BCAT   0x2400000  // float [1024]
#define OFF_FUSED  0x2500000  // float [2][4096][1280]  -> ws end 77 MB
#define OFF_T      0x180000   // reuse (post-encoder)
#define OFF_H1     0x1200000  // reuse
#define OFF_T2     0x2200000  // reuse

// ---------------- helpers ----------------
__device__ __forceinline__ unsigned fkey_flip(float f) {
  unsigned u = __float_as_uint(f);
  return u ^ ((u >> 31) ? 0xFFFFFFFFu : 0x80000000u);
}
__device__ __forceinline__ float fkey_unflip(unsigned k) {
  unsigned u = k ^ ((k >> 31) ? 0x80000000u : 0xFFFFFFFFu);
  return __uint_as_float(u);
}

template<int CTRL>
__device__ __forceinline__ float dpp_max_stepf(float v) {
  int t = __builtin_amdgcn_update_dpp(__float_as_int(v), __float_as_int(v),
                                      CTRL, 0xf, 0xf, false);
  return fmaxf(v, __int_as_float(t));
}
__device__ __forceinline__ float wave64_max(float v) {
  v = dpp_max_stepf<0x111>(v);
  v = dpp_max_stepf<0x112>(v);
  v = dpp_max_stepf<0x114>(v);
  v = dpp_max_stepf<0x118>(v);
  v = dpp_max_stepf<0x142>(v);
  v = dpp_max_stepf<0x143>(v);
  return __int_as_float(__builtin_amdgcn_readlane(__float_as_int(v), 63));
}
template<int CTRL>
__device__ __forceinline__ float dpp_min_stepf(float v) {
  int t = __builtin_amdgcn_update_dpp(__float_as_int(v), __float_as_int(v),
                                      CTRL, 0xf, 0xf, false);
  return fminf(v, __int_as_float(t));
}
__device__ __forceinline__ float wave64_min(float v) {
  v = dpp_min_stepf<0x111>(v);
  v = dpp_min_stepf<0x112>(v);
  v = dpp_min_stepf<0x114>(v);
  v = dpp_min_stepf<0x118>(v);
  v = dpp_min_stepf<0x142>(v);
  v = dpp_min_stepf<0x143>(v);
  return __int_as_float(__builtin_amdgcn_readlane(__float_as_int(v), 63));
}
template<int CTRL>
__device__ __forceinline__ unsigned dpp_min_stepu(unsigned v) {
  unsigned t = (unsigned)__builtin_amdgcn_update_dpp((int)v, (int)v,
                                                     CTRL, 0xf, 0xf, false);
  return v < t ? v : t;
}
__device__ __forceinline__ unsigned wave64_min_u32(unsigned v) {
  v = dpp_min_stepu<0x111>(v);
  v = dpp_min_stepu<0x112>(v);
  v = dpp_min_stepu<0x114>(v);
  v = dpp_min_stepu<0x118>(v);
  v = dpp_min_stepu<0x142>(v);
  v = dpp_min_stepu<0x143>(v);
  return (unsigned)__builtin_amdgcn_readlane((int)v, 63);
}
__device__ __forceinline__ unsigned long long u64max(unsigned long long a,
                                                    unsigned long long b) {
  return a > b ? a : b;
}
__device__ __forceinline__ unsigned spread3(unsigned v) {
  return (v & 1u) | ((v & 2u) << 2) | ((v & 4u) << 4);
}

// ---------------- FPS with stateless chunk skip: one block per batch ----------------
// Setup: Morton counting sort -> 64 chunks of 64 consecutive sorted points + bboxes.
// Per iteration (round-5 shape, ONE reduce tail): lanes 0..7 bound-check chunks;
// chunk skipped iff mindist^2(c,bbox)*margin > wm_prev (uniform) -- then every
// point p in it has d_new(p) > wm_prev >= dist(p), so the min-update is a no-op.
// No cached state: running max rescans all 8 register dists. Tie-break = min spk
// (orig-idx-major) via one u32 DPP chain => exact first-occurrence argmax.
__global__ __launch_bounds__(512) void fps_kernel(const float* __restrict__ x,
                                                  int* __restrict__ cent)
{
  int b = blockIdx.x, tid = threadIdx.x;
  int wid = tid >> 6, lane = tid & 63;
  __shared__ float4 ss4[4096];                 // sorted (x,y,z,asfloat(origidx))
  __shared__ float bb[64 * 6];                 // chunk bboxes
  __shared__ unsigned hist[512];
  __shared__ unsigned sc[512];
  __shared__ unsigned bbm[6];                  // flipped-u32 global bbox
  __shared__ __align__(16) unsigned long long slots[2][8];

  // ---- load original points ----
  float px[8], py[8], pz[8], dist[8];
  unsigned spk[8];
#pragma unroll
  for (int i = 0; i < 8; ++i) {
    int p = tid + 512 * i;
    const float* r = x + ((long)b * 4096 + p) * 6;
    px[i] = r[0]; py[i] = r[1]; pz[i] = r[2];
  }
  if (tid < 6) bbm[tid] = (tid < 3) ? 0xFFFFFFFFu : 0u;
  hist[tid] = 0u;
  if (tid == 0) cent[b * 2048] = 0;
  __syncthreads();

  // ---- global bbox (flipped-u32 atomics; grouping only) ----
  {
    float lx = px[0], hx = px[0], ly = py[0], hy = py[0], lz = pz[0], hz = pz[0];
#pragma unroll
    for (int i = 1; i < 8; ++i) {
      lx = fminf(lx, px[i]); hx = fmaxf(hx, px[i]);
      ly = fminf(ly, py[i]); hy = fmaxf(hy, py[i]);
      lz = fminf(lz, pz[i]); hz = fmaxf(hz, pz[i]);
    }
    lx = wave64_min(lx); hx = wave64_max(hx);
    ly = wave64_min(ly); hy = wave64_max(hy);
    lz = wave64_min(lz); hz = wave64_max(hz);
    if (lane == 0) {
      atomicMin(&bbm[0], fkey_flip(lx)); atomicMax(&bbm[3], fkey_flip(hx));
      atomicMin(&bbm[1], fkey_flip(ly)); atomicMax(&bbm[4], fkey_flip(hy));
      atomicMin(&bbm[2], fkey_flip(lz)); atomicMax(&bbm[5], fkey_flip(hz));
    }
  }
  __syncthreads();
  float lox = fkey_unflip(bbm[0]), loy = fkey_unflip(bbm[1]), loz = fkey_unflip(bbm[2]);
  float hix = fkey_unflip(bbm[3]), hiy = fkey_unflip(bbm[4]), hiz = fkey_unflip(bbm[5]);
  float sxf = (hix > lox) ? 8.0f / (hix - lox) : 0.0f;
  float syf = (hiy > loy) ? 8.0f / (hiy - loy) : 0.0f;
  float szf = (hiz > loz) ? 8.0f / (hiz - loz) : 0.0f;

  // ---- histogram ----
#pragma unroll
  for (int i = 0; i < 8; ++i) {
    int ix = min(7, max(0, (int)((px[i] - lox) * sxf)));
    int iy = min(7, max(0, (int)((py[i] - loy) * syf)));
    int iz = min(7, max(0, (int)((pz[i] - loz) * szf)));
    unsigned cell = spread3((unsigned)ix) | (spread3((unsigned)iy) << 1)
                  | (spread3((unsigned)iz) << 2);
    atomicAdd(&hist[cell], 1u);
  }
  __syncthreads();

  // ---- exclusive scan (Hillis-Steele) ----
  unsigned myc = hist[tid];
  unsigned run = myc;
  for (int s = 1; s < 512; s <<= 1) {
    sc[tid] = run;
    __syncthreads();
    if (tid >= s) run += sc[tid - s];
    __syncthreads();
  }
  hist[tid] = run - myc;
  __syncthreads();

  // ---- scatter ----
#pragma unroll
  for (int i = 0; i < 8; ++i) {
    int ix = min(7, max(0, (int)((px[i] - lox) * sxf)));
    int iy = min(7, max(0, (int)((py[i] - loy) * syf)));
    int iz = min(7, max(0, (int)((pz[i] - loz) * szf)));
    unsigned cell = spread3((unsigned)ix) | (spread3((unsigned)iy) << 1)
                  | (spread3((unsigned)iz) << 2);
    unsigned pos = atomicAdd(&hist[cell], 1u);
    ss4[pos] = make_float4(px[i], py[i], pz[i],
                           __uint_as_float((unsigned)(tid + 512 * i)));
  }
  __syncthreads();

  // ---- reload in sorted order; chunk (wid,i) = positions wid*512+i*64+lane ----
#pragma unroll
  for (int i = 0; i < 8; ++i) {
    int pos = wid * 512 + i * 64 + lane;
    float4 c = ss4[pos];
    px[i] = c.x; py[i] = c.y; pz[i] = c.z;
    unsigned oidx = __float_as_uint(c.w);
    spk[i] = (oidx << 12) | (unsigned)pos;   // orig-idx-major packed key
    dist[i] = 1e10f;
  }

  // ---- chunk bboxes ----
#pragma unroll
  for (int i = 0; i < 8; ++i) {
    float lx = wave64_min(px[i]), hx = wave64_max(px[i]);
    float ly = wave64_min(py[i]), hy = wave64_max(py[i]);
    float lz = wave64_min(pz[i]), hz = wave64_max(pz[i]);
    if (lane == 0) {
      float* bp = &bb[(wid * 8 + i) * 6];
      bp[0] = lx; bp[1] = hx; bp[2] = ly; bp[3] = hy; bp[4] = lz; bp[5] = hz;
    }
  }
  __syncthreads();
  float blox = 0, bhxx = 0, bloy = 0, bhxy = 0, bloz = 0, bhxz = 0;
  if (lane < 8) {
    const float* bp = &bb[(wid * 8 + lane) * 6];
    blox = bp[0]; bhxx = bp[1]; bloy = bp[2]; bhxy = bp[3]; bloz = bp[4]; bhxz = bp[5];
  }

  // ---- initial centroid = original point 0 ----
  const float* r0 = x + (long)b * 4096 * 6;
  float cx = r0[0], cy = r0[1], cz = r0[2];
  float wm = 1e30f;                    // previous-iteration global max (uniform)

  // ---- main loop ----
  for (int j = 1; j < 2048; ++j) {
    // chunk skip check (lanes 0..7): update needed iff bound can't prove no-op
    float dxm = fmaxf(fmaxf(blox - cx, cx - bhxx), 0.0f);
    float dym = fmaxf(fmaxf(bloy - cy, cy - bhxy), 0.0f);
    float dzm = fmaxf(fmaxf(bloz - cz, cz - bhxz), 0.0f);
    float md2 = dxm * dxm + dym * dym + dzm * dzm;
    bool need = (lane < 8) && (md2 <= wm * 1.00002f);
    unsigned long long umask = __ballot(need) & 0xFFull;
    float m = -1.0f;
#pragma unroll
    for (int i = 0; i < 8; ++i) {
      if (umask & (1ull << i)) {
        // exact replica of sum((xyz-c)**2,-1): ((dx*dx+dy*dy)+dz*dz), no FMA
        float dx = __fsub_rn(px[i], cx);
        float dy = __fsub_rn(py[i], cy);
        float dz = __fsub_rn(pz[i], cz);
        float d  = __fadd_rn(__fadd_rn(__fmul_rn(dx, dx), __fmul_rn(dy, dy)),
                             __fmul_rn(dz, dz));
        dist[i] = fminf(dist[i], d);
      }
      m = fmaxf(m, dist[i]);
    }
    float wmw = wave64_max(m);
    unsigned il = 0xFFFFFFFFu;
#pragma unroll
    for (int i = 0; i < 8; ++i)
      if (dist[i] == wmw) il = min(il, spk[i]);
    unsigned wi = wave64_min_u32(il);
    if (lane == 0)
      slots[j & 1][wid] = ((unsigned long long)__float_as_uint(wmw) << 24)
                        | (unsigned long long)(((~(wi >> 12)) & 0xFFFu) << 12)
                        | (unsigned long long)(wi & 0xFFFu);
    __syncthreads();                   // the only barrier per iteration
    const unsigned long long* sl = slots[j & 1];
    ulonglong2 sA = *(const ulonglong2*)&sl[0];
    ulonglong2 sB = *(const ulonglong2*)&sl[2];
    ulonglong2 sC = *(const ulonglong2*)&sl[4];
    ulonglong2 sD = *(const ulonglong2*)&sl[6];
    unsigned long long kk = u64max(u64max(u64max(sA.x, sA.y), u64max(sB.x, sB.y)),
                                   u64max(u64max(sC.x, sC.y), u64max(sD.x, sD.y)));
    unsigned pos  = (unsigned)(kk & 0xFFFu);
    unsigned oidx = (~((unsigned)(kk >> 12))) & 0xFFFu;
    wm = __uint_as_float((unsigned)(kk >> 24));
    float4 c = ss4[pos];
    cx = c.x; cy = c.y; cz = c.z;
    if (tid == 0) cent[b * 2048 + j] = (int)oidx;
  }
}

// ---------------- gather subsampled points ----------------
__global__ void gather_xs_kernel(const float* __restrict__ x, const int* __restrict__ cent,
                                 float* __restrict__ xs6, float4* __restrict__ xsp)
{
  int t = blockIdx.x * 256 + threadIdx.x;
  if (t >= 2 * 2048) return;
  int b = t >> 11;
  int p = cent[t];
  const float* src = x + ((long)b * 4096 + p) * 6;
  float* dst = xs6 + (long)t * 6;
#pragma unroll
  for (int c = 0; c < 6; ++c) dst[c] = src[c];
  xsp[t] = make_float4(src[0], src[1], src[2], 0.0f);
}

// ---------------- kNN: one wave per query ----------------
template<int S, int K>
__global__ __launch_bounds__(256) void knn_kernel(const float4* __restrict__ xsp,
                                                  int* __restrict__ out)
{
  constexpr int NI = S / 64;
  __shared__ float4 P[S];
  int b = (blockIdx.x * 4) / S;
  int wid = threadIdx.x >> 6, lane = threadIdx.x & 63;
  int s = (blockIdx.x * 4 + wid) & (S - 1);
  for (int i = threadIdx.x; i < S; i += 256) P[i] = xsp[b * 2048 + i];
  __syncthreads();
  float4 Q = P[s];
  float saq = __fadd_rn(__fadd_rn(__fmul_rn(Q.x,Q.x), __fmul_rn(Q.y,Q.y)), __fmul_rn(Q.z,Q.z));
  float dd[NI];
#pragma unroll
  for (int i = 0; i < NI; ++i) {
    float4 c = P[i * 64 + lane];
    float sac = __fadd_rn(__fadd_rn(__fmul_rn(c.x,c.x), __fmul_rn(c.y,c.y)), __fmul_rn(c.z,c.z));
    float dot = __fadd_rn(__fadd_rn(__fmul_rn(Q.x,c.x), __fmul_rn(Q.y,c.y)), __fmul_rn(Q.z,c.z));
    dd[i] = __fsub_rn(__fadd_rn(saq, sac), __fmul_rn(2.0f, dot));
  }
  long obase = ((long)b * S + s) * K;
  for (int t = 0; t < K; ++t) {
    float bv = INFINITY; int bi = 0;
#pragma unroll
    for (int i = 0; i < NI; ++i) if (dd[i] < bv) { bv = dd[i]; bi = i; }
    unsigned long long key = ((unsigned long long)fkey_flip(bv) << 32)
                           | (unsigned)(bi * 64 + lane);
#pragma unroll
    for (int m = 32; m; m >>= 1) {
      unsigned long long o = __shfl_xor(key, m, 64);
      if (o < key) key = o;
    }
    unsigned cand = (unsigned)key;
    if ((int)(cand & 63) == lane) {
      int slot = cand >> 6;
#pragma unroll
      for (int i = 0; i < NI; ++i) if (i == slot) dd[i] = INFINITY;
    }
    if (lane == 0) out[obase + t] = (int)cand;
  }
}

// ---------------- Wcat prep ----------------
__global__ void wcat_prep(const float* __restrict__ W, const float* __restrict__ bias,
                          int C, int Cp, float* __restrict__ Wcat, float* __restrict__ bcat)
{
  int n2 = 2 * Cp;
  int total = C * n2;
  for (int t = blockIdx.x * 256 + threadIdx.x; t < total + n2; t += gridDim.x * 256) {
    if (t < total) {
      int c = t / n2, n = t % n2;
      Wcat[t] = (n < Cp) ? (W[c * Cp + n] - W[(C + c) * Cp + n]) : W[(C + c) * Cp + (n - Cp)];
    } else {
      int n = t - total;
      bcat[n] = (n < Cp) ? bias[n] : 0.0f;
    }
  }
}

// ---------------- generic fp32 GEMM (64x64 tile) ----------------
__global__ __launch_bounds__(256) void gemm_bias(
    const float* __restrict__ A, long strideA, int lda,
    const float* __restrict__ W, int N, int K,
    const float* __restrict__ bias,
    float* __restrict__ C, long strideC, int ldc)
{
  A += (long)blockIdx.z * strideA;
  C += (long)blockIdx.z * strideC;
  int rowBase = blockIdx.x * 64, colBase = blockIdx.y * 64;
  __shared__ float As[16][68];
  __shared__ float Ws[16][68];
  int tid = threadIdx.x;
  int tx = tid & 15, ty = tid >> 4;
  float acc[4][4] = {};
  for (int k0 = 0; k0 < K; k0 += 16) {
    {
      int r = tid >> 2, c0 = (tid & 3) * 4;
      const float* Ar = A + (long)(rowBase + r) * lda + k0 + c0;
#pragma unroll
      for (int u = 0; u < 4; ++u) {
        float val = 0.0f;
        if (k0 + c0 + u < K) val = Ar[u];
        As[c0 + u][r] = val;
      }
    }
    {
      int c = tid & 63, kr = tid >> 6;
#pragma unroll
      for (int u = 0; u < 4; ++u) {
        int kk = kr + u * 4;
        float val = 0.0f;
        if (k0 + kk < K) val = W[(long)(k0 + kk) * N + colBase + c];
        Ws[kk][c] = val;
      }
    }
    __syncthreads();
#pragma unroll
    for (int kk = 0; kk < 16; ++kk) {
      float4 av = *(const float4*)&As[kk][ty * 4];
      float4 wv = *(const float4*)&Ws[kk][tx * 4];
      float a_[4] = {av.x, av.y, av.z, av.w};
      float w_[4] = {wv.x, wv.y, wv.z, wv.w};
#pragma unroll
      for (int i = 0; i < 4; ++i)
#pragma unroll
        for (int j = 0; j < 4; ++j)
          acc[i][j] = fmaf(a_[i], w_[j], acc[i][j]);
    }
    __syncthreads();
  }
#pragma unroll
  for (int i = 0; i < 4; ++i) {
    int r = rowBase + ty * 4 + i;
    int c0 = colBase + tx * 4;
    float4 o;
    o.x = acc[i][0] + bias[c0 + 0];
    o.y = acc[i][1] + bias[c0 + 1];
    o.z = acc[i][2] + bias[c0 + 2];
    o.w = acc[i][3] + bias[c0 + 3];
    *(float4*)&C[(long)r * ldc + c0] = o;
  }
}

// ---------------- big fp32 GEMM: 128x128 tile, 8x8 acc/thread ----------------
__global__ __launch_bounds__(256) void gemm_bias_big(
    const float* __restrict__ A, int lda,
    const float* __restrict__ W, int N, int K,
    const float* __restrict__ bias,
    float* __restrict__ C, int ldc)
{
  int rowBase = blockIdx.x * 128, colBase = blockIdx.y * 128;
  __shared__ float As[16][132];
  __shared__ float Ws[16][132];
  int tid = threadIdx.x;
  int tx = tid & 15, ty = tid >> 4;
  float acc[8][8] = {};
  for (int k0 = 0; k0 < K; k0 += 16) {
    {
      int r = tid >> 1, c0 = (tid & 1) * 8;
      const float* Ar = A + (long)(rowBase + r) * lda + k0 + c0;
      float4 v0 = *(const float4*)(Ar);
      float4 v1 = *(const float4*)(Ar + 4);
      As[c0 + 0][r] = v0.x; As[c0 + 1][r] = v0.y; As[c0 + 2][r] = v0.z; As[c0 + 3][r] = v0.w;
      As[c0 + 4][r] = v1.x; As[c0 + 5][r] = v1.y; As[c0 + 6][r] = v1.z; As[c0 + 7][r] = v1.w;
    }
    {
      int kr = tid >> 4, c0 = (tid & 15) * 8;
      const float* Wr = W + (long)(k0 + kr) * N + colBase + c0;
      float4 w0 = *(const float4*)(Wr);
      float4 w1 = *(const float4*)(Wr + 4);
      *(float4*)&Ws[kr][c0]     = w0;
      *(float4*)&Ws[kr][c0 + 4] = w1;
    }
    __syncthreads();
#pragma unroll
    for (int kk = 0; kk < 16; ++kk) {
      float a_[8], w_[8];
      *(float4*)&a_[0] = *(const float4*)&As[kk][ty * 8];
      *(float4*)&a_[4] = *(const float4*)&As[kk][ty * 8 + 4];
      *(float4*)&w_[0] = *(const float4*)&Ws[kk][tx * 8];
      *(float4*)&w_[4] = *(const float4*)&Ws[kk][tx * 8 + 4];
#pragma unroll
      for (int i = 0; i < 8; ++i)
#pragma unroll
        for (int jj = 0; jj < 8; ++jj)
          acc[i][jj] = fmaf(a_[i], w_[jj], acc[i][jj]);
    }
    __syncthreads();
  }
#pragma unroll
  for (int i = 0; i < 8; ++i) {
    int r = rowBase + ty * 8 + i;
    int c0 = colBase + tx * 8;
    float4 o0, o1;
    o0.x = acc[i][0] + bias[c0 + 0];
    o0.y = acc[i][1] + bias[c0 + 1];
    o0.z = acc[i][2] + bias[c0 + 2];
    o0.w = acc[i][3] + bias[c0 + 3];
    o1.x = acc[i][4] + bias[c0 + 4];
    o1.y = acc[i][5] + bias[c0 + 5];
    o1.z = acc[i][6] + bias[c0 + 6];
    o1.w = acc[i][7] + bias[c0 + 7];
    *(float4*)&C[(long)r * ldc + c0]     = o0;
    *(float4*)&C[(long)r * ldc + c0 + 4] = o1;
  }
}

// ---------------- edge aggregation (float4): F[s] = relu(u[s] + max_j v[nbr_j]) ----------------
__global__ void edge_agg(const float* __restrict__ UV, const int* __restrict__ idx,
                         int S, int k, int Cp, float* __restrict__ F)
{
  int bs = blockIdx.x;
  int b = bs / S;
  __shared__ int nb[64];
  if ((int)threadIdx.x < k) nb[threadIdx.x] = idx[(long)bs * k + threadIdx.x];
  __syncthreads();
  int ld = 2 * Cp;
  int nf4 = Cp >> 2;
  for (int c4 = threadIdx.x; c4 < nf4; c4 += blockDim.x) {
    float4 m = make_float4(-INFINITY, -INFINITY, -INFINITY, -INFINITY);
    for (int j = 0; j < k; ++j) {
      const float4* vp = (const float4*)(UV + (long)(b * S + nb[j]) * ld + Cp);
      float4 v = vp[c4];
      m.x = fmaxf(m.x, v.x); m.y = fmaxf(m.y, v.y);
      m.z = fmaxf(m.z, v.z); m.w = fmaxf(m.w, v.w);
    }
    float4 u = ((const float4*)(UV + (long)bs * ld))[c4];
    float4 o;
    o.x = u.x + m.x; o.y = u.y + m.y; o.z = u.z + m.z; o.w = u.w + m.w;
    o.x = o.x > 0.0f ? o.x : 0.0f;
    o.y = o.y > 0.0f ? o.y : 0.0f;
    o.z = o.z > 0.0f ? o.z : 0.0f;
    o.w = o.w > 0.0f ? o.w : 0.0f;
    ((float4*)(F + (long)bs * Cp))[c4] = o;
  }
}

// ---------------- upsample (float4 gather): 3-NN inverse-distance interp ----------------
template<int S, int CP>
__global__ __launch_bounds__(256) void upsample_kernel(
    const float* __restrict__ x, const float4* __restrict__ xsp,
    const float* __restrict__ G, float* __restrict__ fused, int colOff)
{
  constexpr int NI = S / 64;
  __shared__ float4 P[S];
  int b = (blockIdx.x * 4) >> 12;
  int wid = threadIdx.x >> 6, lane = threadIdx.x & 63;
  int n = (blockIdx.x * 4 + wid) & 4095;
  for (int i = threadIdx.x; i < S; i += 256) P[i] = xsp[b * 2048 + i];
  __syncthreads();
  const float* q = x + ((long)b * 4096 + n) * 6;
  float qx = q[0], qy = q[1], qz = q[2];
  float saq = __fadd_rn(__fadd_rn(__fmul_rn(qx,qx), __fmul_rn(qy,qy)), __fmul_rn(qz,qz));
  float dd[NI];
#pragma unroll
  for (int i = 0; i < NI; ++i) {
    float4 c = P[i * 64 + lane];
    float sac = __fadd_rn(__fadd_rn(__fmul_rn(c.x,c.x), __fmul_rn(c.y,c.y)), __fmul_rn(c.z,c.z));
    float dot = __fadd_rn(__fadd_rn(__fmul_rn(qx,c.x), __fmul_rn(qy,c.y)), __fmul_rn(qz,c.z));
    dd[i] = __fsub_rn(__fadd_rn(saq, sac), __fmul_rn(2.0f, dot));
  }
  int id[3]; float w[3];
  for (int t = 0; t < 3; ++t) {
    float bv = INFINITY; int bi = 0;
#pragma unroll
    for (int i = 0; i < NI; ++i) if (dd[i] < bv) { bv = dd[i]; bi = i; }
    unsigned long long key = ((unsigned long long)fkey_flip(bv) << 32)
                           | (unsigned)(bi * 64 + lane);
#pragma unroll
    for (int m = 32; m; m >>= 1) {
      unsigned long long o = __shfl_xor(key, m, 64);
      if (o < key) key = o;
    }
    unsigned cand = (unsigned)key;
    float d2 = fkey_unflip((unsigned)(key >> 32));
    float d = __fsqrt_rn(fmaxf(d2, 0.0f));
    id[t] = (int)cand;
    w[t] = 1.0f / __fadd_rn(d, 1e-8f);
    if ((int)(cand & 63) == lane) {
      int slot = cand >> 6;
#pragma unroll
      for (int i = 0; i < NI; ++i) if (i == slot) dd[i] = INFINITY;
    }
  }
  float wsum = __fadd_rn(__fadd_rn(w[0], w[1]), w[2]);
  float w0 = w[0] / wsum, w1 = w[1] / wsum, w2 = w[2] / wsum;
  const float4* g0 = (const float4*)(G + (long)(b * S + id[0]) * CP);
  const float4* g1 = (const float4*)(G + (long)(b * S + id[1]) * CP);
  const float4* g2 = (const float4*)(G + (long)(b * S + id[2]) * CP);
  float4* orow = (float4*)(fused + ((long)b * 4096 + n) * 1280 + colOff);
#pragma unroll
  for (int t = 0; t < CP / 256; ++t) {
    int c4 = lane + 64 * t;
    float4 a = g0[c4], bb4 = g1[c4], cc = g2[c4];
    float4 v;
    v.x = __fadd_rn(__fadd_rn(__fmul_rn(w0, a.x), __fmul_rn(w1, bb4.x)), __fmul_rn(w2, cc.x));
    v.y = __fadd_rn(__fadd_rn(__fmul_rn(w0, a.y), __fmul_rn(w1, bb4.y)), __fmul_rn(w2, cc.y));
    v.z = __fadd_rn(__fadd_rn(__fmul_rn(w0, a.z), __fmul_rn(w1, bb4.z)), __fmul_rn(w2, cc.z));
    v.w = __fadd_rn(__fadd_rn(__fmul_rn(w0, a.w), __fmul_rn(w1, bb4.w)), __fmul_rn(w2, cc.w));
    orow[c4] = v;
  }
}

// ---------------- GroupNorm(32,512) + relu (+ optional pos-enc) ----------------
__global__ __launch_bounds__(256) void gn_kernel(const float* __restrict__ T,
    const float* __restrict__ gw, const float* __restrict__ gb,
    float* __restrict__ out, int addPos)
{
  int t = blockIdx.x * 256 + threadIdx.x;
  int row = t >> 5, g = t & 31;
  const float* p = T + (long)row * 512 + g * 16;
  float v[16];
#pragma unroll
  for (int i = 0; i < 4; ++i) {
    float4 f = *(const float4*)(p + i * 4);
    v[i*4+0] = f.x; v[i*4+1] = f.y; v[i*4+2] = f.z; v[i*4+3] = f.w;
  }
  float s = 0.0f;
#pragma unroll
  for (int i = 0; i < 16; ++i) s += v[i];
  float mu = s * 0.0625f;
  float var = 0.0f;
#pragma unroll
  for (int i = 0; i < 16; ++i) { float d = v[i] - mu; var += d * d; }
  var *= 0.0625f;
  float inv = 1.0f / sqrtf(var + 1e-5f);
  int cbase = g * 16;
  int n = row & 4095;
  float o[16];
#pragma unroll
  for (int i = 0; i < 16; ++i) {
    int c = cbase + i;
    float y = (v[i] - mu) * inv * gw[c] + gb[c];
    y = y > 0.0f ? y : 0.0f;
    if (addPos) {
      int half = c >> 1;
      float div = expf((float)(2 * half) * -0.017988946039016358f); // -ln(10000)/512
      float ang = (float)n * div;
      y += (c & 1) ? cosf(ang) : sinf(ang);
    }
    o[i] = y;
  }
  float* d = out + (long)row * 512 + cbase;
#pragma unroll
  for (int i = 0; i < 4; ++i) {
    float4 f; f.x = o[i*4+0]; f.y = o[i*4+1]; f.z = o[i*4+2]; f.w = o[i*4+3];
    *(float4*)(d + i * 4) = f;
  }
}

// ---------------- host-side launch helpers ----------------
static inline void launch_gemm(const float* A, long strideA, int lda,
                               const float* W, const float* bias,
                               float* C, long strideC, int ldc,
                               int Mb, int N, int K, int nb, hipStream_t s)
{
  dim3 grid(Mb / 64, N / 64, nb);
  gemm_bias<<<grid, 256, 0, s>>>(A, strideA, lda, W, N, K, bias, C, strideC, ldc);
}
static inline void launch_gemm_big(const float* A, int lda,
                                   const float* W, const float* bias,
                                   float* C, int ldc,
                                   int M, int N, int K, hipStream_t s)
{
  dim3 grid(M / 128, N / 128, 1);
  gemm_bias_big<<<grid, 256, 0, s>>>(A, lda, W, N, K, bias, C, ldc);
}
static inline void launch_edge(const float* UV, const int* knn, int S, int k, int Cp,
                               float* F, hipStream_t s)
{
  int threads = Cp / 4 < 64 ? 64 : Cp / 4;
  edge_agg<<<dim3(2 * S), threads, 0, s>>>(UV, knn, S, k, Cp, F);
}

extern "C" void kernel_launch(void* const* d_in, const int* in_sizes, int n_in,
                              void* d_out, int out_size, void* d_ws, size_t ws_size,
                              hipStream_t stream)
{
  const float* x     = (const float*)d_in[0];
  const float* e1_W0 = (const float*)d_in[1];  const float* e1_b0 = (const float*)d_in[2];
  const float* e1_W1 = (const float*)d_in[3];  const float* e1_b1 = (const float*)d_in[4];
  const float* e1_Wo = (const float*)d_in[5];  const float* e1_bo = (const float*)d_in[6];
  const float* e2_W0 = (const float*)d_in[7];  const float* e2_b0 = (const float*)d_in[8];
  const float* e2_W1 = (const float*)d_in[9];  const float* e2_b1 = (const float*)d_in[10];
  const float* e2_Wo = (const float*)d_in[11]; const float* e2_bo = (const float*)d_in[12];
  const float* e3_W0 = (const float*)d_in[13]; const float* e3_b0 = (const float*)d_in[14];
  const float* e3_W1 = (const float*)d_in[15]; const float* e3_b1 = (const float*)d_in[16];
  const float* e3_W2 = (const float*)d_in[17]; const float* e3_b2 = (const float*)d_in[18];
  const float* e3_Wo = (const float*)d_in[19]; const float* e3_bo = (const float*)d_in[20];
  const float* f_W1  = (const float*)d_in[21]; const float* f_b1  = (const float*)d_in[22];
  const float* g1_w  = (const float*)d_in[23]; const float* g1_b  = (const float*)d_in[24];
  const float* f_W2  = (const float*)d_in[25]; const float* f_b2  = (const float*)d_in[26];
  const float* g2_w  = (const float*)d_in[27]; const float* g2_b  = (const float*)d_in[28];

  char* ws = (char*)d_ws;
  int*    cent  = (int*)(ws + OFF_CENT);
  float4* xsp   = (float4*)(ws + OFF_XSP);
  float*  xs6   = (float*)(ws + OFF_XS6);
  int*    knn   = (int*)(ws + OFF_KNN);
  float*  F     = (float*)(ws + OFF_F);
  float*  UV    = (float*)(ws + OFF_UV);
  float*  G     = (float*)(ws + OFF_G);
  float*  WCAT  = (float*)(ws + OFF_WCAT);
  float*  BCAT  = (float*)(ws + OFF_BCAT);
  float*  FUSED = (float*)(ws + OFF_FUSED);
  float*  T     = (float*)(ws + OFF_T);
  float*  H1    = (float*)(ws + OFF_H1);
  float*  T2    = (float*)(ws + OFF_T2);

  fps_kernel<<<2, 512, 0, stream>>>(x, cent);
  gather_xs_kernel<<<16, 256, 0, stream>>>(x, cent, xs6, xsp);

  // ---- encoder 1: S=512, k=16, 6->128->256, proj 256 ----
  knn_kernel<512,16><<<256, 256, 0, stream>>>(xsp, knn);
  wcat_prep<<<256, 256, 0, stream>>>(e1_W0, e1_b0, 6, 128, WCAT, BCAT);
  launch_gemm(xs6, (long)2048*6, 6, WCAT, BCAT, UV, (long)512*256, 256, 512, 256, 6, 2, stream);
  launch_edge(UV, knn, 512, 16, 128, F, stream);
  wcat_prep<<<256, 256, 0, stream>>>(e1_W1, e1_b1, 128, 256, WCAT, BCAT);
  launch_gemm(F, 0, 128, WCAT, BCAT, UV, 0, 512, 1024, 512, 128, 1, stream);
  launch_edge(UV, knn, 512, 16, 256, F, stream);
  launch_gemm(F, 0, 256, e1_Wo, e1_bo, G, 0, 256, 1024, 256, 256, 1, stream);
  upsample_kernel<512,256><<<2048, 256, 0, stream>>>(x, xsp, G, FUSED, 0);

  // ---- encoder 2: S=1024, k=32, 6->256->512, proj 512 ----
  knn_kernel<1024,32><<<512, 256, 0, stream>>>(xsp, knn);
  wcat_prep<<<256, 256, 0, stream>>>(e2_W0, e2_b0, 6, 256, WCAT, BCAT);
  launch_gemm(xs6, (long)2048*6, 6, WCAT, BCAT, UV, (long)1024*512, 512, 1024, 512, 6, 2, stream);
  launch_edge(UV, knn, 1024, 32, 256, F, stream);
  wcat_prep<<<256, 256, 0, stream>>>(e2_W1, e2_b1, 256, 512, WCAT, BCAT);
  launch_gemm_big(F, 256, WCAT, BCAT, UV, 1024, 2048, 1024, 256, stream);
  launch_edge(UV, knn, 1024, 32, 512, F, stream);
  launch_gemm(F, 0, 512, e2_Wo, e2_bo, G, 0, 512, 2048, 512, 512, 1, stream);
  upsample_kernel<1024,512><<<2048, 256, 0, stream>>>(x, xsp, G, FUSED, 256);

  // ---- encoder 3: S=2048, k=64, 6->128->256->512, proj 512 ----
  knn_kernel<2048,64><<<1024, 256, 0, stream>>>(xsp, knn);
  wcat_prep<<<256, 256, 0, stream>>>(e3_W0, e3_b0, 6, 128, WCAT, BCAT);
  launch_gemm(xs6, (long)2048*6, 6, WCAT, BCAT, UV, (long)2048*256, 256, 2048, 256, 6, 2, stream);
  launch_edge(UV, knn, 2048, 64, 128, F, stream);
  wcat_prep<<<256, 256, 0, stream>>>(e3_W1, e3_b1, 128, 256, WCAT, BCAT);
  launch_gemm_big(F, 128, WCAT, BCAT, UV, 512, 4096, 512, 128, stream);
  launch_edge(UV, knn, 2048, 64, 256, F, stream);
  wcat_prep<<<256, 256, 0, stream>>>(e3_W2, e3_b2, 256, 512, WCAT, BCAT);
  launch_gemm_big(F, 256, WCAT, BCAT, UV, 1024, 4096, 1024, 256, stream);
  launch_edge(UV, knn, 2048, 64, 512, F, stream);
  launch_gemm_big(F, 512, e3_Wo, e3_bo, G, 512, 4096, 512, 512, stream);
  upsample_kernel<2048,512><<<2048, 256, 0, stream>>>(x, xsp, G, FUSED, 768);

  // ---- fusion MLP + GroupNorm + pos-enc ----
  launch_gemm_big(FUSED, 1280, f_W1, f_b1, T, 512, 8192, 512, 1280, stream);
  gn_kernel<<<1024, 256, 0, stream>>>(T, g1_w, g1_b, H1, 0);
  launch_gemm_big(H1, 512, f_W2, f_b2, T2, 512, 8192, 512, 512, stream);
  gn_kernel<<<1024, 256, 0, stream>>>(T2, g2_w, g2_b, (float*)d_out, 1);
}

// Round 8
// 1862.507 us; speedup vs baseline: 2.1182x; 1.3006x over previous
//
#include <hip/hip_runtime.h>
#include <math.h>

// ---------------- workspace offsets (bytes) ----------------
#define OFF_CENT   0x0        // int [2][2048]
#define OFF_XSP    0x20000    // float4 [2][2048]
#define OFF_XS6    0x40000    // float [2][2048][6]
#define OFF_KNN    0x60000    // int [2][2048][64] max
#define OFF_F      0x180000   // float [2*2048][512] max
#define OFF_UV     0xA00000   // float [2*2048][1024] max
#define OFF_G      0x1A00000  // float [2*2048][512] max
#define OFF_WCAT   0x2200000  // float [256][1024] max
#define OFF_BCAT   0x2400000  // float [1024]
#define OFF_FUSED  0x2500000  // float [2][4096][1280]  -> ws end 77 MB
#define OFF_T      0x180000   // reuse (post-encoder)
#define OFF_H1     0x1200000  // reuse
#define OFF_T2     0x2200000  // reuse

// ---------------- helpers ----------------
__device__ __forceinline__ unsigned fkey_flip(float f) {
  unsigned u = __float_as_uint(f);
  return u ^ ((u >> 31) ? 0xFFFFFFFFu : 0x80000000u);
}
__device__ __forceinline__ float fkey_unflip(unsigned k) {
  unsigned u = k ^ ((k >> 31) ? 0x80000000u : 0xFFFFFFFFu);
  return __uint_as_float(u);
}

template<int CTRL>
__device__ __forceinline__ float dpp_max_stepf(float v) {
  int t = __builtin_amdgcn_update_dpp(__float_as_int(v), __float_as_int(v),
                                      CTRL, 0xf, 0xf, false);
  return fmaxf(v, __int_as_float(t));
}
__device__ __forceinline__ float wave64_max(float v) {
  v = dpp_max_stepf<0x111>(v);  // row_shr:1
  v = dpp_max_stepf<0x112>(v);  // row_shr:2
  v = dpp_max_stepf<0x114>(v);  // row_shr:4
  v = dpp_max_stepf<0x118>(v);  // row_shr:8
  v = dpp_max_stepf<0x142>(v);  // row_bcast:15
  v = dpp_max_stepf<0x143>(v);  // row_bcast:31
  return __int_as_float(__builtin_amdgcn_readlane(__float_as_int(v), 63));
}
__device__ __forceinline__ unsigned long long u64max(unsigned long long a,
                                                    unsigned long long b) {
  return a > b ? a : b;
}

// ---------------- FPS (round-5 verbatim, measured best 1261us) ----------------
// 512 threads (8 waves). Per wave: f32 DPP max + ballot tie-break (no second
// DPP chain). One barrier/iter; double-buffered 8-slot u64 exchange.
__global__ __launch_bounds__(512) void fps_kernel(const float* __restrict__ x,
                                                  int* __restrict__ cent)
{
  int b = blockIdx.x, tid = threadIdx.x;
  __shared__ float4 C4[4096];
  __shared__ __align__(16) unsigned long long slots[2][8];
  float px[8], py[8], pz[8], dist[8];
#pragma unroll
  for (int i = 0; i < 8; ++i) {
    int p = tid + 512 * i;
    const float* r = x + ((long)b * 4096 + p) * 6;
    px[i] = r[0]; py[i] = r[1]; pz[i] = r[2];
    C4[p] = make_float4(px[i], py[i], pz[i], 0.0f);
    dist[i] = 1e10f;
  }
  if (tid == 0) cent[b * 2048] = 0;
  __syncthreads();
  float4 c0 = C4[0];
  float cx = c0.x, cy = c0.y, cz = c0.z;
  int wid = tid >> 6, lane = tid & 63;
  for (int j = 1; j < 2048; ++j) {
    float m = -1.0f;
#pragma unroll
    for (int i = 0; i < 8; ++i) {
      // exact replica of sum((xyz-c)**2, -1): ((dx*dx+dy*dy)+dz*dz), no FMA
      float dx = __fsub_rn(px[i], cx);
      float dy = __fsub_rn(py[i], cy);
      float dz = __fsub_rn(pz[i], cz);
      float d  = __fadd_rn(__fadd_rn(__fmul_rn(dx,dx), __fmul_rn(dy,dy)), __fmul_rn(dz,dz));
      float nd = fminf(dist[i], d);
      dist[i] = nd;
      m = fmaxf(m, nd);
    }
    float wm = wave64_max(m);
    // tie-break: lowest i (global idx is i-major), then lowest lane.
    unsigned long long mm = 0ULL; unsigned ii = 0;
#pragma unroll
    for (int i = 7; i >= 0; --i) {        // descending: lowest nonzero i wins last
      unsigned long long mi = __ballot(dist[i] == wm);
      if (mi) { mm = mi; ii = (unsigned)i; }
    }
    int lane_w = __ffsll((unsigned long long)mm) - 1;  // mm != 0 within this wave
    unsigned idx_w = (unsigned)(wid * 64 + lane_w) + 512u * ii;
    if (lane == 0)
      slots[j & 1][wid] = ((unsigned long long)__float_as_uint(wm) << 32)
                        | (unsigned)(0xFFFFFFFFu - idx_w);
    __syncthreads();                      // the only barrier per iteration
    const unsigned long long* sl = slots[j & 1];
    ulonglong2 sA = *(const ulonglong2*)&sl[0];
    ulonglong2 sB = *(const ulonglong2*)&sl[2];
    ulonglong2 sC = *(const ulonglong2*)&sl[4];
    ulonglong2 sD = *(const ulonglong2*)&sl[6];
    unsigned long long kk = u64max(u64max(u64max(sA.x, sA.y), u64max(sB.x, sB.y)),
                                   u64max(u64max(sC.x, sC.y), u64max(sD.x, sD.y)));
    unsigned idx = 0xFFFFFFFFu - (unsigned)kk;
    float4 c = C4[idx];
    cx = c.x; cy = c.y; cz = c.z;
    if (tid == 0) cent[b * 2048 + j] = idx;
  }
}

// ---------------- gather subsampled points ----------------
__global__ void gather_xs_kernel(const float* __restrict__ x, const int* __restrict__ cent,
                                 float* __restrict__ xs6, float4* __restrict__ xsp)
{
  int t = blockIdx.x * 256 + threadIdx.x;
  if (t >= 2 * 2048) return;
  int b = t >> 11;
  int p = cent[t];
  const float* src = x + ((long)b * 4096 + p) * 6;
  float* dst = xs6 + (long)t * 6;
#pragma unroll
  for (int c = 0; c < 6; ++c) dst[c] = src[c];
  xsp[t] = make_float4(src[0], src[1], src[2], 0.0f);
}

// ---------------- kNN: one wave per query ----------------
template<int S, int K>
__global__ __launch_bounds__(256) void knn_kernel(const float4* __restrict__ xsp,
                                                  int* __restrict__ out)
{
  constexpr int NI = S / 64;
  __shared__ float4 P[S];
  int b = (blockIdx.x * 4) / S;
  int wid = threadIdx.x >> 6, lane = threadIdx.x & 63;
  int s = (blockIdx.x * 4 + wid) & (S - 1);
  for (int i = threadIdx.x; i < S; i += 256) P[i] = xsp[b * 2048 + i];
  __syncthreads();
  float4 Q = P[s];
  float saq = __fadd_rn(__fadd_rn(__fmul_rn(Q.x,Q.x), __fmul_rn(Q.y,Q.y)), __fmul_rn(Q.z,Q.z));
  float dd[NI];
#pragma unroll
  for (int i = 0; i < NI; ++i) {
    float4 c = P[i * 64 + lane];
    float sac = __fadd_rn(__fadd_rn(__fmul_rn(c.x,c.x), __fmul_rn(c.y,c.y)), __fmul_rn(c.z,c.z));
    float dot = __fadd_rn(__fadd_rn(__fmul_rn(Q.x,c.x), __fmul_rn(Q.y,c.y)), __fmul_rn(Q.z,c.z));
    dd[i] = __fsub_rn(__fadd_rn(saq, sac), __fmul_rn(2.0f, dot));
  }
  long obase = ((long)b * S + s) * K;
  for (int t = 0; t < K; ++t) {
    float bv = INFINITY; int bi = 0;
#pragma unroll
    for (int i = 0; i < NI; ++i) if (dd[i] < bv) { bv = dd[i]; bi = i; }
    unsigned long long key = ((unsigned long long)fkey_flip(bv) << 32)
                           | (unsigned)(bi * 64 + lane);
#pragma unroll
    for (int m = 32; m; m >>= 1) {
      unsigned long long o = __shfl_xor(key, m, 64);
      if (o < key) key = o;
    }
    unsigned cand = (unsigned)key;
    if ((int)(cand & 63) == lane) {
      int slot = cand >> 6;
#pragma unroll
      for (int i = 0; i < NI; ++i) if (i == slot) dd[i] = INFINITY;
    }
    if (lane == 0) out[obase + t] = (int)cand;
  }
}

// ---------------- Wcat prep ----------------
__global__ void wcat_prep(const float* __restrict__ W, const float* __restrict__ bias,
                          int C, int Cp, float* __restrict__ Wcat, float* __restrict__ bcat)
{
  int n2 = 2 * Cp;
  int total = C * n2;
  for (int t = blockIdx.x * 256 + threadIdx.x; t < total + n2; t += gridDim.x * 256) {
    if (t < total) {
      int c = t / n2, n = t % n2;
      Wcat[t] = (n < Cp) ? (W[c * Cp + n] - W[(C + c) * Cp + n]) : W[(C + c) * Cp + (n - Cp)];
    } else {
      int n = t - total;
      bcat[n] = (n < Cp) ? bias[n] : 0.0f;
    }
  }
}

// ---------------- generic fp32 GEMM (64x64 tile) for K=6 ----------------
__global__ __launch_bounds__(256) void gemm_bias(
    const float* __restrict__ A, long strideA, int lda,
    const float* __restrict__ W, int N, int K,
    const float* __restrict__ bias,
    float* __restrict__ C, long strideC, int ldc)
{
  A += (long)blockIdx.z * strideA;
  C += (long)blockIdx.z * strideC;
  int rowBase = blockIdx.x * 64, colBase = blockIdx.y * 64;
  __shared__ float As[16][68];
  __shared__ float Ws[16][68];
  int tid = threadIdx.x;
  int tx = tid & 15, ty = tid >> 4;
  float acc[4][4] = {};
  for (int k0 = 0; k0 < K; k0 += 16) {
    {
      int r = tid >> 2, c0 = (tid & 3) * 4;
      const float* Ar = A + (long)(rowBase + r) * lda + k0 + c0;
#pragma unroll
      for (int u = 0; u < 4; ++u) {
        float val = 0.0f;
        if (k0 + c0 + u < K) val = Ar[u];
        As[c0 + u][r] = val;
      }
    }
    {
      int c = tid & 63, kr = tid >> 6;
#pragma unroll
      for (int u = 0; u < 4; ++u) {
        int kk = kr + u * 4;
        float val = 0.0f;
        if (k0 + kk < K) val = W[(long)(k0 + kk) * N + colBase + c];
        Ws[kk][c] = val;
      }
    }
    __syncthreads();
#pragma unroll
    for (int kk = 0; kk < 16; ++kk) {
      float4 av = *(const float4*)&As[kk][ty * 4];
      float4 wv = *(const float4*)&Ws[kk][tx * 4];
      float a_[4] = {av.x, av.y, av.z, av.w};
      float w_[4] = {wv.x, wv.y, wv.z, wv.w};
#pragma unroll
      for (int i = 0; i < 4; ++i)
#pragma unroll
        for (int j = 0; j < 4; ++j)
          acc[i][j] = fmaf(a_[i], w_[j], acc[i][j]);
    }
    __syncthreads();
  }
#pragma unroll
  for (int i = 0; i < 4; ++i) {
    int r = rowBase + ty * 4 + i;
    int c0 = colBase + tx * 4;
    float4 o;
    o.x = acc[i][0] + bias[c0 + 0];
    o.y = acc[i][1] + bias[c0 + 1];
    o.z = acc[i][2] + bias[c0 + 2];
    o.w = acc[i][3] + bias[c0 + 3];
    *(float4*)&C[(long)r * ldc + c0] = o;
  }
}

// ---------------- MFMA split-bf16 GEMM: 128x128 tile, 4 waves, BK=32 ----------------
// fp32 a = bf16(hi) + bf16(lo residual); D += hi*hi + lo*hi + hi*lo  (~2^-16 rel err).
// A/B frag layout (16x16x32): row/col = lane&15, k = (lane>>4)*8 + e.
// C/D layout [measured m89]: col = lane&15, row = (lane>>4)*4 + reg.
typedef __attribute__((ext_vector_type(8))) short bf16x8;
typedef __attribute__((ext_vector_type(4))) float f32x4;

__device__ __forceinline__ unsigned short f2bf_rn(float f) {
  unsigned u = __float_as_uint(f);
  unsigned r = u + 0x7FFFu + ((u >> 16) & 1u);
  return (unsigned short)(r >> 16);
}
__device__ __forceinline__ float bf2f(unsigned short h) {
  return __uint_as_float(((unsigned)h) << 16);
}
__device__ __forceinline__ void cvt4(const float4 v, int2& hi, int2& lo) {
  unsigned short h0 = f2bf_rn(v.x), h1 = f2bf_rn(v.y);
  unsigned short h2 = f2bf_rn(v.z), h3 = f2bf_rn(v.w);
  unsigned short l0 = f2bf_rn(v.x - bf2f(h0)), l1 = f2bf_rn(v.y - bf2f(h1));
  unsigned short l2 = f2bf_rn(v.z - bf2f(h2)), l3 = f2bf_rn(v.w - bf2f(h3));
  hi.x = (int)((unsigned)h0 | ((unsigned)h1 << 16));
  hi.y = (int)((unsigned)h2 | ((unsigned)h3 << 16));
  lo.x = (int)((unsigned)l0 | ((unsigned)l1 << 16));
  lo.y = (int)((unsigned)l2 | ((unsigned)l3 << 16));
}

__global__ __launch_bounds__(256) void gemm_mfma(
    const float* __restrict__ A, int lda,
    const float* __restrict__ W, int N, int K,
    const float* __restrict__ bias,
    float* __restrict__ C, int ldc)
{
  __shared__ unsigned short Ah[128][40], Al[128][40];   // [row][k], 80B stride
  __shared__ unsigned short Bh[128][40], Bl[128][40];   // [col][k] (transposed)
  int tid = threadIdx.x;
  int lane = tid & 63, wv = tid >> 6;
  int wr = wv >> 1, wc = wv & 1;            // wave quadrant of the 128x128 tile
  int l15 = lane & 15, l16 = lane >> 4;
  int rowBase = blockIdx.x * 128, colBase = blockIdx.y * 128;
  f32x4 acc[4][4];
#pragma unroll
  for (int mb = 0; mb < 4; ++mb)
#pragma unroll
    for (int nb = 0; nb < 4; ++nb) acc[mb][nb] = 0.0f;

  int r_st = tid >> 1, h_st = tid & 1;      // staging assignment
  for (int k0 = 0; k0 < K; k0 += 32) {
    {   // stage A: row r_st, 16 floats at k0 + h_st*16
      const float* Ap = A + (long)(rowBase + r_st) * lda + k0 + h_st * 16;
#pragma unroll
      for (int e = 0; e < 16; e += 4) {
        float4 v = *(const float4*)(Ap + e);
        int2 hi, lo; cvt4(v, hi, lo);
        *(int2*)&Ah[r_st][h_st * 16 + e] = hi;
        *(int2*)&Al[r_st][h_st * 16 + e] = lo;
      }
    }
    {   // stage B transposed: col r_st, 16 k at k0 + h_st*16
      const float* Wp = W + (long)(k0 + h_st * 16) * N + colBase + r_st;
#pragma unroll
      for (int e = 0; e < 16; e += 4) {
        float4 v;
        v.x = Wp[(long)(e + 0) * N];
        v.y = Wp[(long)(e + 1) * N];
        v.z = Wp[(long)(e + 2) * N];
        v.w = Wp[(long)(e + 3) * N];
        int2 hi, lo; cvt4(v, hi, lo);
        *(int2*)&Bh[r_st][h_st * 16 + e] = hi;
        *(int2*)&Bl[r_st][h_st * 16 + e] = lo;
      }
    }
    __syncthreads();
    bf16x8 ah[4], al[4], bh[4], bl[4];
#pragma unroll
    for (int mb = 0; mb < 4; ++mb) {
      int r = wr * 64 + mb * 16 + l15;
      ah[mb] = *(const bf16x8*)&Ah[r][l16 * 8];
      al[mb] = *(const bf16x8*)&Al[r][l16 * 8];
    }
#pragma unroll
    for (int nb = 0; nb < 4; ++nb) {
      int c = wc * 64 + nb * 16 + l15;
      bh[nb] = *(const bf16x8*)&Bh[c][l16 * 8];
      bl[nb] = *(const bf16x8*)&Bl[c][l16 * 8];
    }
#pragma unroll
    for (int mb = 0; mb < 4; ++mb)
#pragma unroll
      for (int nb = 0; nb < 4; ++nb) {
        acc[mb][nb] = __builtin_amdgcn_mfma_f32_16x16x32_bf16(ah[mb], bh[nb], acc[mb][nb], 0, 0, 0);
        acc[mb][nb] = __builtin_amdgcn_mfma_f32_16x16x32_bf16(al[mb], bh[nb], acc[mb][nb], 0, 0, 0);
        acc[mb][nb] = __builtin_amdgcn_mfma_f32_16x16x32_bf16(ah[mb], bl[nb], acc[mb][nb], 0, 0, 0);
      }
    __syncthreads();
  }
#pragma unroll
  for (int mb = 0; mb < 4; ++mb)
#pragma unroll
    for (int nb = 0; nb < 4; ++nb) {
      int c = colBase + wc * 64 + nb * 16 + l15;
      float bs = bias[c];
#pragma unroll
      for (int r = 0; r < 4; ++r) {
        int row = rowBase + wr * 64 + mb * 16 + l16 * 4 + r;
        C[(long)row * ldc + c] = acc[mb][nb][r] + bs;
      }
    }
}

// ---------------- edge aggregation (float4) ----------------
__global__ void edge_agg(const float* __restrict__ UV, const int* __restrict__ idx,
                         int S, int k, int Cp, float* __restrict__ F)
{
  int bs = blockIdx.x;
  int b = bs / S;
  __shared__ int nb[64];
  if ((int)threadIdx.x < k) nb[threadIdx.x] = idx[(long)bs * k + threadIdx.x];
  __syncthreads();
  int ld = 2 * Cp;
  int nf4 = Cp >> 2;
  for (int c4 = threadIdx.x; c4 < nf4; c4 += blockDim.x) {
    float4 m = make_float4(-INFINITY, -INFINITY, -INFINITY, -INFINITY);
    for (int j = 0; j < k; ++j) {
      const float4* vp = (const float4*)(UV + (long)(b * S + nb[j]) * ld + Cp);
      float4 v = vp[c4];
      m.x = fmaxf(m.x, v.x); m.y = fmaxf(m.y, v.y);
      m.z = fmaxf(m.z, v.z); m.w = fmaxf(m.w, v.w);
    }
    float4 u = ((const float4*)(UV + (long)bs * ld))[c4];
    float4 o;
    o.x = u.x + m.x; o.y = u.y + m.y; o.z = u.z + m.z; o.w = u.w + m.w;
    o.x = o.x > 0.0f ? o.x : 0.0f;
    o.y = o.y > 0.0f ? o.y : 0.0f;
    o.z = o.z > 0.0f ? o.z : 0.0f;
    o.w = o.w > 0.0f ? o.w : 0.0f;
    ((float4*)(F + (long)bs * Cp))[c4] = o;
  }
}

// ---------------- upsample (float4 gather) ----------------
template<int S, int CP>
__global__ __launch_bounds__(256) void upsample_kernel(
    const float* __restrict__ x, const float4* __restrict__ xsp,
    const float* __restrict__ G, float* __restrict__ fused, int colOff)
{
  constexpr int NI = S / 64;
  __shared__ float4 P[S];
  int b = (blockIdx.x * 4) >> 12;
  int wid = threadIdx.x >> 6, lane = threadIdx.x & 63;
  int n = (blockIdx.x * 4 + wid) & 4095;
  for (int i = threadIdx.x; i < S; i += 256) P[i] = xsp[b * 2048 + i];
  __syncthreads();
  const float* q = x + ((long)b * 4096 + n) * 6;
  float qx = q[0], qy = q[1], qz = q[2];
  float saq = __fadd_rn(__fadd_rn(__fmul_rn(qx,qx), __fmul_rn(qy,qy)), __fmul_rn(qz,qz));
  float dd[NI];
#pragma unroll
  for (int i = 0; i < NI; ++i) {
    float4 c = P[i * 64 + lane];
    float sac = __fadd_rn(__fadd_rn(__fmul_rn(c.x,c.x), __fmul_rn(c.y,c.y)), __fmul_rn(c.z,c.z));
    float dot = __fadd_rn(__fadd_rn(__fmul_rn(qx,c.x), __fmul_rn(qy,c.y)), __fmul_rn(qz,c.z));
    dd[i] = __fsub_rn(__fadd_rn(saq, sac), __fmul_rn(2.0f, dot));
  }
  int id[3]; float w[3];
  for (int t = 0; t < 3; ++t) {
    float bv = INFINITY; int bi = 0;
#pragma unroll
    for (int i = 0; i < NI; ++i) if (dd[i] < bv) { bv = dd[i]; bi = i; }
    unsigned long long key = ((unsigned long long)fkey_flip(bv) << 32)
                           | (unsigned)(bi * 64 + lane);
#pragma unroll
    for (int m = 32; m; m >>= 1) {
      unsigned long long o = __shfl_xor(key, m, 64);
      if (o < key) key = o;
    }
    unsigned cand = (unsigned)key;
    float d2 = fkey_unflip((unsigned)(key >> 32));
    float d = __fsqrt_rn(fmaxf(d2, 0.0f));
    id[t] = (int)cand;
    w[t] = 1.0f / __fadd_rn(d, 1e-8f);
    if ((int)(cand & 63) == lane) {
      int slot = cand >> 6;
#pragma unroll
      for (int i = 0; i < NI; ++i) if (i == slot) dd[i] = INFINITY;
    }
  }
  float wsum = __fadd_rn(__fadd_rn(w[0], w[1]), w[2]);
  float w0 = w[0] / wsum, w1 = w[1] / wsum, w2 = w[2] / wsum;
  const float4* g0 = (const float4*)(G + (long)(b * S + id[0]) * CP);
  const float4* g1 = (const float4*)(G + (long)(b * S + id[1]) * CP);
  const float4* g2 = (const float4*)(G + (long)(b * S + id[2]) * CP);
  float4* orow = (float4*)(fused + ((long)b * 4096 + n) * 1280 + colOff);
#pragma unroll
  for (int t = 0; t < CP / 256; ++t) {
    int c4 = lane + 64 * t;
    float4 a = g0[c4], bb4 = g1[c4], cc = g2[c4];
    float4 v;
    v.x = __fadd_rn(__fadd_rn(__fmul_rn(w0, a.x), __fmul_rn(w1, bb4.x)), __fmul_rn(w2, cc.x));
    v.y = __fadd_rn(__fadd_rn(__fmul_rn(w0, a.y), __fmul_rn(w1, bb4.y)), __fmul_rn(w2, cc.y));
    v.z = __fadd_rn(__fadd_rn(__fmul_rn(w0, a.z), __fmul_rn(w1, bb4.z)), __fmul_rn(w2, cc.z));
    v.w = __fadd_rn(__fadd_rn(__fmul_rn(w0, a.w), __fmul_rn(w1, bb4.w)), __fmul_rn(w2, cc.w));
    orow[c4] = v;
  }
}

// ---------------- GroupNorm(32,512) + relu (+ optional pos-enc) ----------------
__global__ __launch_bounds__(256) void gn_kernel(const float* __restrict__ T,
    const float* __restrict__ gw, const float* __restrict__ gb,
    float* __restrict__ out, int addPos)
{
  int t = blockIdx.x * 256 + threadIdx.x;
  int row = t >> 5, g = t & 31;
  const float* p = T + (long)row * 512 + g * 16;
  float v[16];
#pragma unroll
  for (int i = 0; i < 4; ++i) {
    float4 f = *(const float4*)(p + i * 4);
    v[i*4+0] = f.x; v[i*4+1] = f.y; v[i*4+2] = f.z; v[i*4+3] = f.w;
  }
  float s = 0.0f;
#pragma unroll
  for (int i = 0; i < 16; ++i) s += v[i];
  float mu = s * 0.0625f;
  float var = 0.0f;
#pragma unroll
  for (int i = 0; i < 16; ++i) { float d = v[i] - mu; var += d * d; }
  var *= 0.0625f;
  float inv = 1.0f / sqrtf(var + 1e-5f);
  int cbase = g * 16;
  int n = row & 4095;
  float o[16];
#pragma unroll
  for (int i = 0; i < 16; ++i) {
    int c = cbase + i;
    float y = (v[i] - mu) * inv * gw[c] + gb[c];
    y = y > 0.0f ? y : 0.0f;
    if (addPos) {
      int half = c >> 1;
      float div = expf((float)(2 * half) * -0.017988946039016358f); // -ln(10000)/512
      float ang = (float)n * div;
      y += (c & 1) ? cosf(ang) : sinf(ang);
    }
    o[i] = y;
  }
  float* d = out + (long)row * 512 + cbase;
#pragma unroll
  for (int i = 0; i < 4; ++i) {
    float4 f; f.x = o[i*4+0]; f.y = o[i*4+1]; f.z = o[i*4+2]; f.w = o[i*4+3];
    *(float4*)(d + i * 4) = f;
  }
}

// ---------------- host-side launch helpers ----------------
static inline void launch_gemm(const float* A, long strideA, int lda,
                               const float* W, const float* bias,
                               float* C, long strideC, int ldc,
                               int Mb, int N, int K, int nb, hipStream_t s)
{
  dim3 grid(Mb / 64, N / 64, nb);
  gemm_bias<<<grid, 256, 0, s>>>(A, strideA, lda, W, N, K, bias, C, strideC, ldc);
}
static inline void launch_mfma(const float* A, int lda,
                               const float* W, const float* bias,
                               float* C, int ldc,
                               int M, int N, int K, hipStream_t s)
{
  dim3 grid(M / 128, N / 128, 1);
  gemm_mfma<<<grid, 256, 0, s>>>(A, lda, W, N, K, bias, C, ldc);
}
static inline void launch_edge(const float* UV, const int* knn, int S, int k, int Cp,
                               float* F, hipStream_t s)
{
  int threads = Cp / 4 < 64 ? 64 : Cp / 4;
  edge_agg<<<dim3(2 * S), threads, 0, s>>>(UV, knn, S, k, Cp, F);
}

extern "C" void kernel_launch(void* const* d_in, const int* in_sizes, int n_in,
                              void* d_out, int out_size, void* d_ws, size_t ws_size,
                              hipStream_t stream)
{
  const float* x     = (const float*)d_in[0];
  const float* e1_W0 = (const float*)d_in[1];  const float* e1_b0 = (const float*)d_in[2];
  const float* e1_W1 = (const float*)d_in[3];  const float* e1_b1 = (const float*)d_in[4];
  const float* e1_Wo = (const float*)d_in[5];  const float* e1_bo = (const float*)d_in[6];
  const float* e2_W0 = (const float*)d_in[7];  const float* e2_b0 = (const float*)d_in[8];
  const float* e2_W1 = (const float*)d_in[9];  const float* e2_b1 = (const float*)d_in[10];
  const float* e2_Wo = (const float*)d_in[11]; const float* e2_bo = (const float*)d_in[12];
  const float* e3_W0 = (const float*)d_in[13]; const float* e3_b0 = (const float*)d_in[14];
  const float* e3_W1 = (const float*)d_in[15]; const float* e3_b1 = (const float*)d_in[16];
  const float* e3_W2 = (const float*)d_in[17]; const float* e3_b2 = (const float*)d_in[18];
  const float* e3_Wo = (const float*)d_in[19]; const float* e3_bo = (const float*)d_in[20];
  const float* f_W1  = (const float*)d_in[21]; const float* f_b1  = (const float*)d_in[22];
  const float* g1_w  = (const float*)d_in[23]; const float* g1_b  = (const float*)d_in[24];
  const float* f_W2  = (const float*)d_in[25]; const float* f_b2  = (const float*)d_in[26];
  const float* g2_w  = (const float*)d_in[27]; const float* g2_b  = (const float*)d_in[28];

  char* ws = (char*)d_ws;
  int*    cent  = (int*)(ws + OFF_CENT);
  float4* xsp   = (float4*)(ws + OFF_XSP);
  float*  xs6   = (float*)(ws + OFF_XS6);
  int*    knn   = (int*)(ws + OFF_KNN);
  float*  F     = (float*)(ws + OFF_F);
  float*  UV    = (float*)(ws + OFF_UV);
  float*  G     = (float*)(ws + OFF_G);
  float*  WCAT  = (float*)(ws + OFF_WCAT);
  float*  BCAT  = (float*)(ws + OFF_BCAT);
  float*  FUSED = (float*)(ws + OFF_FUSED);
  float*  T     = (float*)(ws + OFF_T);
  float*  H1    = (float*)(ws + OFF_H1);
  float*  T2    = (float*)(ws + OFF_T2);

  fps_kernel<<<2, 512, 0, stream>>>(x, cent);
  gather_xs_kernel<<<16, 256, 0, stream>>>(x, cent, xs6, xsp);

  // ---- encoder 1: S=512, k=16, 6->128->256, proj 256 ----
  knn_kernel<512,16><<<256, 256, 0, stream>>>(xsp, knn);
  wcat_prep<<<256, 256, 0, stream>>>(e1_W0, e1_b0, 6, 128, WCAT, BCAT);
  launch_gemm(xs6, (long)2048*6, 6, WCAT, BCAT, UV, (long)512*256, 256, 512, 256, 6, 2, stream);
  launch_edge(UV, knn, 512, 16, 128, F, stream);
  wcat_prep<<<256, 256, 0, stream>>>(e1_W1, e1_b1, 128, 256, WCAT, BCAT);
  launch_mfma(F, 128, WCAT, BCAT, UV, 512, 1024, 512, 128, stream);
  launch_edge(UV, knn, 512, 16, 256, F, stream);
  launch_mfma(F, 256, e1_Wo, e1_bo, G, 256, 1024, 256, 256, stream);
  upsample_kernel<512,256><<<2048, 256, 0, stream>>>(x, xsp, G, FUSED, 0);

  // ---- encoder 2: S=1024, k=32, 6->256->512, proj 512 ----
  knn_kernel<1024,32><<<512, 256, 0, stream>>>(xsp, knn);
  wcat_prep<<<256, 256, 0, stream>>>(e2_W0, e2_b0, 6, 256, WCAT, BCAT);
  launch_gemm(xs6, (long)2048*6, 6, WCAT, BCAT, UV, (long)1024*512, 512, 1024, 512, 6, 2, stream);
  launch_edge(UV, knn, 1024, 32, 256, F, stream);
  wcat_prep<<<256, 256, 0, stream>>>(e2_W1, e2_b1, 256, 512, WCAT, BCAT);
  launch_mfma(F, 256, WCAT, BCAT, UV, 1024, 2048, 1024, 256, stream);
  launch_edge(UV, knn, 1024, 32, 512, F, stream);
  launch_mfma(F, 512, e2_Wo, e2_bo, G, 512, 2048, 512, 512, stream);
  upsample_kernel<1024,512><<<2048, 256, 0, stream>>>(x, xsp, G, FUSED, 256);

  // ---- encoder 3: S=2048, k=64, 6->128->256->512, proj 512 ----
  knn_kernel<2048,64><<<1024, 256, 0, stream>>>(xsp, knn);
  wcat_prep<<<256, 256, 0, stream>>>(e3_W0, e3_b0, 6, 128, WCAT, BCAT);
  launch_gemm(xs6, (long)2048*6, 6, WCAT, BCAT, UV, (long)2048*256, 256, 2048, 256, 6, 2, stream);
  launch_edge(UV, knn, 2048, 64, 128, F, stream);
  wcat_prep<<<256, 256, 0, stream>>>(e3_W1, e3_b1, 128, 256, WCAT, BCAT);
  launch_mfma(F, 128, WCAT, BCAT, UV, 512, 4096, 512, 128, stream);
  launch_edge(UV, knn, 2048, 64, 256, F, stream);
  wcat_prep<<<256, 256, 0, stream>>>(e3_W2, e3_b2, 256, 512, WCAT, BCAT);
  launch_mfma(F, 256, WCAT, BCAT, UV, 1024, 4096, 1024, 256, stream);
  launch_edge(UV, knn, 2048, 64, 512, F, stream);
  launch_mfma(F, 512, e3_Wo, e3_bo, G, 512, 4096, 512, 512, stream);
  upsample_kernel<2048,512><<<2048, 256, 0, stream>>>(x, xsp, G, FUSED, 768);

  // ---- fusion MLP + GroupNorm + pos-enc ----
  launch_mfma(FUSED, 1280, f_W1, f_b1, T, 512, 8192, 512, 1280, stream);
  gn_kernel<<<1024, 256, 0, stream>>>(T, g1_w, g1_b, H1, 0);
  launch_mfma(H1, 512, f_W2, f_b2, T2, 512, 8192, 512, 512, stream);
  gn_kernel<<<1024, 256, 0, stream>>>(T2, g2_w, g2_b, (float*)d_out, 1);
}